// Round 3
// baseline (551.437 us; speedup 1.0000x reference)
//
#include <hip/hip_runtime.h>
#include <hip/hip_bf16.h>

// Problem constants
#define BB   2
#define SS   2048
#define DD   2560
#define HH   8
#define HKVV 4
#define HDD  256
#define MM   (BB*SS)      // 4096 rows
#define NQ   (HH*HDD)     // 2048
#define NKV  (HKVV*HDD)   // 1024
#define SCALING 0.0625f   // 256^-0.5
#define SOFTCAP 4096.0f
#define CAPC    (1.0f/(3.0f*SOFTCAP*SOFTCAP))  // cubic softcap coefficient
#define M0      20.0f     // fixed softmax max: |scores| <= 16.2 by Cauchy-Schwarz

typedef __attribute__((ext_vector_type(8))) short short8;       // 8 bf16 (4 VGPR)
typedef __attribute__((ext_vector_type(8))) unsigned short ushort8;
typedef __attribute__((ext_vector_type(4))) unsigned short us4;
typedef __attribute__((ext_vector_type(4))) float f32x4;        // MFMA C/D

__device__ __forceinline__ float bf2f(unsigned short u) {
    union { unsigned int i; float f; } v; v.i = ((unsigned int)u) << 16; return v.f;
}
__device__ __forceinline__ unsigned short f2bf(float f) {
    union { float f; unsigned int i; } v; v.f = f;
    return (unsigned short)((v.i + 0x7fffu + ((v.i >> 16) & 1u)) >> 16);
}
__device__ __forceinline__ f32x4 mfma16(short8 a, short8 b, f32x4 c) {
    return __builtin_amdgcn_mfma_f32_16x16x32_bf16(a, b, c, 0, 0, 0);
}

// async global->LDS, 16B per lane (gfx950). LDS dest must be lane-linear.
__device__ __forceinline__ void async_cp16(const void* g, void* l) {
    __builtin_amdgcn_global_load_lds(
        (__attribute__((address_space(1))) void*)(g),
        (__attribute__((address_space(3))) void*)(l), 16, 0, 0);
}

// dtype-polymorphic helpers
__device__ __forceinline__ ushort8 ld8(const unsigned short* p) { return *(const ushort8*)p; }
__device__ __forceinline__ ushort8 ld8(const float* p) {
    ushort8 r;
#pragma unroll
    for (int i = 0; i < 8; i++) r[i] = f2bf(p[i]);
    return r;
}
__device__ __forceinline__ void stc(float* p, float v)          { *p = v; }
__device__ __forceinline__ void stc(unsigned short* p, float v) { *p = f2bf(v); }
// staging: bf16 source -> async DMA; fp32 source -> in-reg convert + LDS write
__device__ __forceinline__ void stage8(const unsigned short* src, unsigned short* lds) {
    async_cp16(src, lds);
}
__device__ __forceinline__ void stage8(const float* src, unsigned short* lds) {
    *(ushort8*)lds = ld8(src);
}

// ---------------------------------------------------------------------------
// fp32 -> bf16 bulk convert (RNE), float4-vectorized grid-stride
// ---------------------------------------------------------------------------
__global__ __launch_bounds__(256) void cvt_bf16(const float* __restrict__ in,
                                                unsigned short* __restrict__ out, int n4)
{
    int i = blockIdx.x * 256 + threadIdx.x;
    const int stride = gridDim.x * 256;
    for (; i < n4; i += stride) {
        float4 v = ((const float4*)in)[i];
        us4 o;
        o[0] = f2bf(v.x); o[1] = f2bf(v.y); o[2] = f2bf(v.z); o[3] = f2bf(v.w);
        ((us4*)out)[i] = o;
    }
}

// ---------------------------------------------------------------------------
// Unified GEMM: C(M,N) = A(M,K) @ B(N,K)^T. bf16 operands staged via
// global_load_lds(16B); fp32 operands converted in-reg. 128x128 tile, 4
// waves. VT_OUT: epilogue writes V^T (b,kvh,d,s) instead of row-major C.
// ---------------------------------------------------------------------------
template<typename TA, typename TB, typename TC, bool VT_OUT>
__global__ __launch_bounds__(256) void gemm_k(const TA* __restrict__ A,
                                              const TB* __restrict__ Bm,
                                              TC* __restrict__ C,
                                              int M, int N, int K)
{
    __shared__ __align__(16) unsigned short As[128][32];
    __shared__ __align__(16) unsigned short Bs[128][32];

    const int tid  = threadIdx.x;
    const int bm   = blockIdx.x, bn = blockIdx.y;
    const int wave = tid >> 6, lane = tid & 63;
    const int quad = lane >> 4, lm = lane & 15;
    const int wm = (wave >> 1) * 64, wn = (wave & 1) * 64;

    f32x4 acc[4][4];
#pragma unroll
    for (int i = 0; i < 4; i++)
#pragma unroll
        for (int j = 0; j < 4; j++) acc[i][j] = (f32x4)0.0f;

    unsigned short* AsF = &As[0][0];
    unsigned short* BsF = &Bs[0][0];
    const int grow = tid >> 2;           // 0..63
    const int gcol = (tid & 3) * 8;      // 0,8,16,24
    const TA* Ab = A  + (size_t)(bm * 128) * K;
    const TB* Bb = Bm + (size_t)(bn * 128) * K;

    for (int k0 = 0; k0 < K; k0 += 32) {
        stage8(&Ab[(size_t)(grow     ) * K + k0 + gcol], AsF + tid * 8);
        stage8(&Ab[(size_t)(grow + 64) * K + k0 + gcol], AsF + 2048 + tid * 8);
        stage8(&Bb[(size_t)(grow     ) * K + k0 + gcol], BsF + tid * 8);
        stage8(&Bb[(size_t)(grow + 64) * K + k0 + gcol], BsF + 2048 + tid * 8);
        __syncthreads();   // drains vmcnt/lgkmcnt -> LDS valid

        short8 af[4], bf[4];
#pragma unroll
        for (int t = 0; t < 4; t++) af[t] = *(const short8*)&As[wm + t * 16 + lm][quad * 8];
#pragma unroll
        for (int t = 0; t < 4; t++) bf[t] = *(const short8*)&Bs[wn + t * 16 + lm][quad * 8];
#pragma unroll
        for (int i = 0; i < 4; i++)
#pragma unroll
            for (int j = 0; j < 4; j++)
                acc[i][j] = mfma16(af[i], bf[j], acc[i][j]);
        __syncthreads();
    }

    // C/D layout: row = quad*4 + r, col = lm  [verified m89/m91]
#pragma unroll
    for (int i = 0; i < 4; i++)
#pragma unroll
        for (int j = 0; j < 4; j++) {
            if constexpr (VT_OUT) {
                int row0 = bm * 128 + wm + i * 16 + quad * 4;   // b*SS + s0
                int col  = bn * 128 + wn + j * 16 + lm;         // kvh*HDD + d
                int b    = row0 >> 11, s0 = row0 & (SS - 1);
                int kvh  = col >> 8,   d  = col & (HDD - 1);
                us4 pk;
#pragma unroll
                for (int r = 0; r < 4; r++) pk[r] = f2bf(acc[i][j][r]);
                *(us4*)&C[(((size_t)b * HKVV + kvh) * HDD + d) * SS + s0] = pk;
            } else {
#pragma unroll
                for (int r = 0; r < 4; r++) {
                    int row = bm * 128 + wm + i * 16 + quad * 4 + r;
                    int col = bn * 128 + wn + j * 16 + lm;
                    stc(&C[(size_t)row * N + col], acc[i][j][r]);
                }
            }
        }
}

// ---------------------------------------------------------------------------
// Fused RMSNorm + RoPE in place on bf16 X (b, s, h, d), one block per (bs,h).
// ---------------------------------------------------------------------------
__global__ __launch_bounds__(256) void norm_rope(unsigned short* __restrict__ X,
                                                 const float* __restrict__ nw,
                                                 const float* __restrict__ cosb,
                                                 const float* __restrict__ sinb,
                                                 int nheads)
{
    const int bs = blockIdx.x;
    const int h  = blockIdx.y;
    const int t  = threadIdx.x;

    __shared__ float xs[256];
    __shared__ float red[4];

    const size_t base = ((size_t)bs * nheads + h) * HDD;
    float v = bf2f(X[base + t]);
    xs[t] = v;

    float p = v * v;
#pragma unroll
    for (int off = 32; off >= 1; off >>= 1) p += __shfl_xor(p, off);
    if ((t & 63) == 0) red[t >> 6] = p;
    __syncthreads();
    float sum = red[0] + red[1] + red[2] + red[3];
    float rs  = rsqrtf(sum * (1.0f / HDD) + 1e-6f);

    const int pt = (t + 128) & 255;
    float w1 = 1.0f + nw[t];
    float w2 = 1.0f + nw[pt];
    float normed  = v * rs * w1;
    float partner = xs[pt] * rs * w2;
    float rot = (t < 128) ? -partner : partner;   // rotate_half: [-x2, x1]
    float c = cosb[(size_t)bs * HDD + t];
    float s = sinb[(size_t)bs * HDD + t];
    X[base + t] = f2bf(normed * c + rot * s);
}

// ---------------------------------------------------------------------------
// Split-key flash attention (Tier A path), 3-blocks/CU edition.
//
// Round-2 diagnosis: after split-key balancing, per-CU-step cost ~2000 cyc
// vs ~560 VALU + ~300 MFMA issue -> ~45% stall; occupancy capped at 25%
// (68 KB LDS -> 2 blocks/CU). Fix: LDS diet to 52 KB (K double-buffered
// 32 KB + V single-buffered 16 KB + Ps 4 KB) -> 3 blocks/CU, 12 waves/CU,
// and all 768 units co-resident (no dispatch tail; heavy-first strided
// assignment = LPT-style balance).
//
// Single-buffered V sync (counted vmcnt, never drain mid-loop):
//   top:  issue K(t+1) -> vmcnt(8)  [waits K(t); V(t)+K(t+1) in flight]
//         barrier -> QK(t) / softmax / P-roundtrip
//         vmcnt(4)  [waits V(t), issued a full step ago -> latency hidden]
//         barrier -> PV(t) -> barrier -> issue V(t+1)
// ---------------------------------------------------------------------------
// units sorted by descending tile count: byte = qb<<2 | (single?2:0) | half
__device__ const unsigned char unit_tbl[48] = {
    62, 124, 125, 120, 121,     // 15s:32  31h:32,32  30h:31,31
    58, 116, 117, 112, 113,     // 14s:30  29h:30,30  28h:29,29
    54, 108, 109, 104, 105,     // 13s:28  27h:28,28  26h:27,27
    50, 100, 101,  96,  97,     // 12s:26  25h:26,26  24h:25,25
    46,  92,  93,  88,  89,     // 11s:24  23h:24,24  22h:23,23
    42,  84,  85,  80,  81,     // 10s:22  21h:22,22  20h:21,21
    38,  76,  77,  72,  73,     //  9s:20  19h:20,20  18h:19,19
    34,  68,  69,  64,  65,     //  8s:18  17h:18,18  16h:17,17
    30,  26,  22,  18,  14, 10, 6, 2   // 7s..0s: 16,14,12,10,8,6,4,2
};

__global__ __launch_bounds__(256) void attn_split(const unsigned short* __restrict__ Q,
                                                  const unsigned short* __restrict__ K,
                                                  const unsigned short* __restrict__ VT,
                                                  unsigned short* __restrict__ O,
                                                  float* __restrict__ Opart,
                                                  float* __restrict__ lpart)
{
    const int tid = threadIdx.x, w = tid >> 6, lane = tid & 63;
    const int quad = lane >> 4, lm = lane & 15;
    const int hb = blockIdx.x;                   // 0..15
    const int h = hb & 7, b = hb >> 3, kvh = h >> 1;

    const unsigned int u = unit_tbl[blockIdx.y];
    const int qb = u >> 2;
    const bool single = (u & 2) != 0;
    const int half = u & 1;
    const int q0 = qb * 64;
    const int T  = 2 * (qb + 1);
    const int t_lo = (!single && half) ? (qb + 1) : 0;
    const int t_hi = single ? T : (half ? T : (qb + 1));

    __shared__ __align__(16) unsigned short Ks[2][32 * 256];   // 32 KB, chunk-swizzled, dbuf
    __shared__ __align__(16) unsigned short Vt[256 * 32];      // 16 KB, (d, s), single buf
    __shared__ __align__(16) unsigned short Ps[4 * 512];       // per-wave P, swizzled

    // Q A-fragments: lane holds Q[m=lm][k=quad*8+j] per 32-wide chunk c
    const unsigned short* Qb = Q + (((size_t)b * SS + q0 + w * 16 + lm) * HH + h) * HDD;
    short8 qf[8];
#pragma unroll
    for (int c = 0; c < 8; c++) qf[c] = *(const short8*)&Qb[c * 32 + quad * 8];

    const unsigned short* Kb = K  + (size_t)b * SS * NKV + (size_t)kvh * HDD;    // row s, stride NKV
    const unsigned short* Vb = VT + ((size_t)b * HKVV + kvh) * HDD * (size_t)SS; // row d, stride SS

    f32x4 o_acc[16];
#pragma unroll
    for (int i = 0; i < 16; i++) o_acc[i] = (f32x4)0.0f;
    float l_r[4] = {0.f, 0.f, 0.f, 0.f};

    const int mylo = q0 + w * 16;                // wave's first q-row
    const int row  = mylo + quad * 4;            // + r = C-layout rows

    // K staging: 4 DMAs/thread (16 KB tile). LDS chunk kc of row krow holds
    // global 16B chunk kc^(krow&7).
    auto STAGE_K = [&](int bi, int k0) {
#pragma unroll
        for (int p = 0; p < 4; p++) {
            const int slot = p * 256 + tid;
            const int krow = slot >> 5, kc = slot & 31;
            async_cp16(&Kb[(size_t)(k0 + krow) * NKV + ((kc ^ (krow & 7)) * 8)],
                       &Ks[bi][slot * 8]);
        }
    };
    // V staging: 4 DMAs/thread. LDS chunk vc of d-row vd holds global chunk
    // vc^((vd>>1)&3).
    auto STAGE_V = [&](int k0) {
#pragma unroll
        for (int p = 0; p < 4; p++) {
            const int slot = p * 256 + tid;
            const int vd = slot >> 2, vc = slot & 3;
            async_cp16(&Vb[(size_t)vd * SS + k0 + ((vc ^ ((vd >> 1) & 3)) * 8)],
                       &Vt[slot * 8]);
        }
    };

    STAGE_K(0, t_lo * 32);
    STAGE_V(t_lo * 32);
    int cur = 0;

    for (int t = t_lo; t < t_hi; t++) {
        const int k0 = t * 32;
        const bool more = (t + 1 < t_hi);

        if (more) {
            STAGE_K(cur ^ 1, k0 + 32);           // prefetch next K tile
            asm volatile("s_waitcnt vmcnt(8)" ::: "memory");  // K(t) done; V(t)+K(t+1) in flight
        } else {
            asm volatile("s_waitcnt vmcnt(4)" ::: "memory");  // K(t) done; V(t) in flight
        }
        __builtin_amdgcn_s_barrier();            // Ks[cur] valid for all waves
        __builtin_amdgcn_sched_barrier(0);

        short8 pf;
        if (k0 <= mylo + 15) {                   // wave has unmasked keys (wave-uniform)
            // ---- S = Q K^T (16 x 32) ----
            f32x4 sa0 = (f32x4)0.0f, sa1 = (f32x4)0.0f;
            __builtin_amdgcn_s_setprio(1);
#pragma unroll
            for (int c = 0; c < 8; c++) {
                const int cs = (((c * 4 + quad) ^ (lm & 7))) * 8;   // un-swizzle
                short8 kf0 = *(const short8*)&Ks[cur][lm * 256 + cs];
                short8 kf1 = *(const short8*)&Ks[cur][(16 + lm) * 256 + cs];
                sa0 = mfma16(qf[c], kf0, sa0);
                sa1 = mfma16(qf[c], kf1, sa1);
            }
            __builtin_amdgcn_s_setprio(0);

            // ---- cubic softcap + fixed-max exp (no cross-lane) ----
            const bool msk = (k0 + 31 > mylo);
            float pe[2][4];
#pragma unroll
            for (int t2 = 0; t2 < 2; t2++) {
                const int key = k0 + t2 * 16 + lm;
#pragma unroll
                for (int r = 0; r < 4; r++) {
                    float s = (t2 ? sa1[r] : sa0[r]) * SCALING;
                    s = s - s * s * s * CAPC;            // ~= SOFTCAP*tanh(s/SOFTCAP)
                    float e = __expf(s - M0);
                    if (msk && key > row + r) e = 0.0f;
                    pe[t2][r] = e;
                    l_r[r] += e;
                }
            }

            // ---- P: C layout -> A layout via swizzled per-wave LDS ----
#pragma unroll
            for (int t2 = 0; t2 < 2; t2++)
#pragma unroll
                for (int r = 0; r < 4; r++) {
                    const int g = (t2 * 2 + (lm >> 3)) ^ r ^ quad;
                    Ps[w * 512 + (quad * 4 + r) * 32 + g * 8 + (lm & 7)] = f2bf(pe[t2][r]);
                }
            asm volatile("s_waitcnt lgkmcnt(0)" ::: "memory");
            __builtin_amdgcn_sched_barrier(0);
            const int gr = quad ^ (lm & 3) ^ (lm >> 2);
            pf = *(const short8*)&Ps[w * 512 + lm * 32 + gr * 8];
        }

        // V(t) was issued a full step ago -> latency already hidden
        if (more) asm volatile("s_waitcnt vmcnt(4)" ::: "memory");  // only K(t+1) in flight
        else      asm volatile("s_waitcnt vmcnt(0)" ::: "memory");
        __builtin_amdgcn_s_barrier();            // Vt valid for all waves
        __builtin_amdgcn_sched_barrier(0);

        if (k0 <= mylo + 15) {
            // ---- O += P V ----
            __builtin_amdgcn_s_setprio(1);
#pragma unroll
            for (int nt = 0; nt < 16; nt++) {
                short8 vf = *(const short8*)&Vt[(nt * 16 + lm) * 32
                                                + ((quad ^ ((lm >> 1) & 3)) * 8)];
                o_acc[nt] = mfma16(pf, vf, o_acc[nt]);
            }
            __builtin_amdgcn_s_setprio(0);
        }

        __builtin_amdgcn_sched_barrier(0);
        __builtin_amdgcn_s_barrier();            // all reads of Vt done
        __builtin_amdgcn_sched_barrier(0);
        if (more) STAGE_V(k0 + 32);              // overwrite Vt with V(t+1)
        cur ^= 1;
    }

    // ---- epilogue: reduce l over 16-lane col group ----
#pragma unroll
    for (int off = 1; off < 16; off <<= 1)
#pragma unroll
        for (int r = 0; r < 4; r++) l_r[r] += __shfl_xor(l_r[r], off);

    if (single) {
        // normalize + store bf16 (in place over Q rows: same linear layout,
        // only this block touches these rows)
#pragma unroll
        for (int r = 0; r < 4; r++) {
            float inv = 1.0f / l_r[r];
            unsigned short* Ob = O + ((size_t)b * SS + row + r) * NQ + h * HDD;
#pragma unroll
            for (int nt = 0; nt < 16; nt++)
                Ob[nt * 16 + lm] = f2bf(o_acc[nt][r] * inv);
        }
    } else {
        // unnormalized f32 partial + l to workspace slot
        const int slot = (((b * HH + h) * 16 + (qb - 16)) << 1) | half;
        float* Ob = Opart + ((size_t)slot * 64 + w * 16 + quad * 4) * 256;
#pragma unroll
        for (int r = 0; r < 4; r++) {
            if (lm == 0) lpart[slot * 64 + w * 16 + quad * 4 + r] = l_r[r];
#pragma unroll
            for (int nt = 0; nt < 16; nt++)
                Ob[(size_t)r * 256 + nt * 16 + lm] = o_acc[nt][r];
        }
    }
}

// combine the two key-half partials for qb 16..31, normalize, write ATT bf16
__global__ __launch_bounds__(256) void attn_reduce(const float* __restrict__ Op,
                                                   const float* __restrict__ lp,
                                                   unsigned short* __restrict__ ATT)
{
    const int sp  = blockIdx.x >> 4;             // ((b*HH+h)*16 + (qb-16)), 0..255
    const int wr0 = (blockIdx.x & 15) * 4;
    const int r   = threadIdx.x >> 6;            // 0..3
    const int c0  = (threadIdx.x & 63) * 4;
    const int wrow = wr0 + r;
    const int qbm = sp & 15, h = (sp >> 4) & 7, b = sp >> 7;

    const size_t base0 = ((size_t)(sp * 2) * 64 + wrow) * 256;
    const size_t base1 = base0 + (size_t)64 * 256;
    float4 a = *(const float4*)&Op[base0 + c0];
    float4 d = *(const float4*)&Op[base1 + c0];
    float l = lp[sp * 2 * 64 + wrow] + lp[(sp * 2 + 1) * 64 + wrow];
    float inv = 1.0f / l;
    us4 o;
    o[0] = f2bf((a.x + d.x) * inv); o[1] = f2bf((a.y + d.y) * inv);
    o[2] = f2bf((a.z + d.z) * inv); o[3] = f2bf((a.w + d.w) * inv);
    const int srow = (16 + qbm) * 64 + wrow;
    *(us4*)&ATT[(((size_t)b * SS + srow) * HH + h) * HDD + c0] = o;
}

// ---------------------------------------------------------------------------
// Legacy single-pass attention (Tiers B/C: no ws room for partials)
// ---------------------------------------------------------------------------
__global__ __launch_bounds__(256) void attn_kernel(const unsigned short* __restrict__ Q,
                                                   const unsigned short* __restrict__ K,
                                                   const unsigned short* __restrict__ VT,
                                                   unsigned short* __restrict__ O)
{
    const int tid = threadIdx.x, w = tid >> 6, lane = tid & 63;
    const int quad = lane >> 4, lm = lane & 15;
    const int h = blockIdx.y, b = blockIdx.z, kvh = h >> 1;

    const int bx = blockIdx.x;                   // 0..31
    const int qb = (bx & 1) ? (31 - (bx >> 1)) : (bx >> 1);
    const int q0 = qb * 64;
    const int T  = 2 * (qb + 1);                 // 32-key tiles (always >= 2)

    __shared__ __align__(16) unsigned short Ks[2][32 * 256];
    __shared__ __align__(16) unsigned short Vt[2][256 * 32];
    __shared__ __align__(16) unsigned short Ps[4 * 512];

    const unsigned short* Qb = Q + (((size_t)b * SS + q0 + w * 16 + lm) * HH + h) * HDD;
    short8 qf[8];
#pragma unroll
    for (int c = 0; c < 8; c++) qf[c] = *(const short8*)&Qb[c * 32 + quad * 8];

    const unsigned short* Kb = K  + (size_t)b * SS * NKV + (size_t)kvh * HDD;
    const unsigned short* Vb = VT + ((size_t)b * HKVV + kvh) * HDD * (size_t)SS;

    f32x4 o_acc[16];
#pragma unroll
    for (int i = 0; i < 16; i++) o_acc[i] = (f32x4)0.0f;
    float l_r[4] = {0.f, 0.f, 0.f, 0.f};

    const int mylo = q0 + w * 16;
    const int row  = mylo + quad * 4;

    auto STAGE = [&](int bi, int k0) {
#pragma unroll
        for (int p = 0; p < 4; p++) {
            const int slot = p * 256 + tid;
            const int krow = slot >> 5, kc = slot & 31;
            async_cp16(&Kb[(size_t)(k0 + krow) * NKV + ((kc ^ (krow & 7)) * 8)],
                       &Ks[bi][slot * 8]);
            const int vd = slot >> 2, vc = slot & 3;
            async_cp16(&Vb[(size_t)vd * SS + k0 + ((vc ^ ((vd >> 1) & 3)) * 8)],
                       &Vt[bi][slot * 8]);
        }
    };

    STAGE(0, 0);
    int cur = 0;

    for (int t = 0; t < T; t++) {
        const int k0 = t * 32;

        if (t + 1 < T) {
            STAGE(cur ^ 1, k0 + 32);
            asm volatile("s_waitcnt vmcnt(8)" ::: "memory");
        } else {
            asm volatile("s_waitcnt vmcnt(0)" ::: "memory");
        }
        __builtin_amdgcn_s_barrier();
        __builtin_amdgcn_sched_barrier(0);

        if (k0 <= mylo + 15) {
            f32x4 sa0 = (f32x4)0.0f, sa1 = (f32x4)0.0f;
            __builtin_amdgcn_s_setprio(1);
#pragma unroll
            for (int c = 0; c < 8; c++) {
                const int cs = (((c * 4 + quad) ^ (lm & 7))) * 8;
                short8 kf0 = *(const short8*)&Ks[cur][lm * 256 + cs];
                short8 kf1 = *(const short8*)&Ks[cur][(16 + lm) * 256 + cs];
                sa0 = mfma16(qf[c], kf0, sa0);
                sa1 = mfma16(qf[c], kf1, sa1);
            }
            __builtin_amdgcn_s_setprio(0);

            const bool msk = (k0 + 31 > mylo);
            float pe[2][4];
#pragma unroll
            for (int t2 = 0; t2 < 2; t2++) {
                const int key = k0 + t2 * 16 + lm;
#pragma unroll
                for (int r = 0; r < 4; r++) {
                    float s = (t2 ? sa1[r] : sa0[r]) * SCALING;
                    s = s - s * s * s * CAPC;
                    float e = __expf(s - M0);
                    if (msk && key > row + r) e = 0.0f;
                    pe[t2][r] = e;
                    l_r[r] += e;
                }
            }

#pragma unroll
            for (int t2 = 0; t2 < 2; t2++)
#pragma unroll
                for (int r = 0; r < 4; r++) {
                    const int g = (t2 * 2 + (lm >> 3)) ^ r ^ quad;
                    Ps[w * 512 + (quad * 4 + r) * 32 + g * 8 + (lm & 7)] = f2bf(pe[t2][r]);
                }
            asm volatile("s_waitcnt lgkmcnt(0)" ::: "memory");
            __builtin_amdgcn_sched_barrier(0);
            const int gr = quad ^ (lm & 3) ^ (lm >> 2);
            short8 pf = *(const short8*)&Ps[w * 512 + lm * 32 + gr * 8];

            __builtin_amdgcn_s_setprio(1);
#pragma unroll
            for (int nt = 0; nt < 16; nt++) {
                short8 vf = *(const short8*)&Vt[cur][(nt * 16 + lm) * 32
                                                    + ((quad ^ ((lm >> 1) & 3)) * 8)];
                o_acc[nt] = mfma16(pf, vf, o_acc[nt]);
            }
            __builtin_amdgcn_s_setprio(0);
        }

        __builtin_amdgcn_sched_barrier(0);
        __builtin_amdgcn_s_barrier();
        __builtin_amdgcn_sched_barrier(0);
        cur ^= 1;
    }

#pragma unroll
    for (int off = 1; off < 16; off <<= 1)
#pragma unroll
        for (int r = 0; r < 4; r++) l_r[r] += __shfl_xor(l_r[r], off);
#pragma unroll
    for (int r = 0; r < 4; r++) {
        float inv = 1.0f / l_r[r];
        unsigned short* Ob = O + ((size_t)b * SS + row + r) * NQ + h * HDD;
#pragma unroll
        for (int nt = 0; nt < 16; nt++)
            Ob[nt * 16 + lm] = f2bf(o_acc[nt][r] * inv);
    }
}

// ---------------------------------------------------------------------------
extern "C" void kernel_launch(void* const* d_in, const int* in_sizes, int n_in,
                              void* d_out, int out_size, void* d_ws, size_t ws_size,
                              hipStream_t stream)
{
    const float* x    = (const float*)d_in[0];
    const float* cosb = (const float*)d_in[1];
    const float* sinb = (const float*)d_in[2];
    // d_in[3] = mask (pure causal + NEG, reimplemented in-kernel)
    const float* q_w  = (const float*)d_in[4];
    const float* k_w  = (const float*)d_in[5];
    const float* v_w  = (const float*)d_in[6];
    const float* o_w  = (const float*)d_in[7];
    const float* qn_w = (const float*)d_in[8];
    const float* kn_w = (const float*)d_in[9];
    float* out = (float*)d_out;

    const size_t sz_xb = (size_t)MM * DD;     // 10485760 shorts
    const size_t sz_wq = (size_t)NQ * DD;     //  5242880
    const size_t sz_wk = (size_t)NKV * DD;    //  2621440
    const size_t sz_q  = (size_t)MM * NQ;     //  8388608
    const size_t sz_k  = (size_t)MM * NKV;    //  4194304

    const size_t needA = (sz_xb + 2 * sz_wq + 2 * sz_wk + sz_q + 2 * sz_k) * 2; // ~86 MB
    const size_t needB = (2 * sz_wq + 2 * sz_wk + sz_q + 2 * sz_k) * 2;         // ~65 MB

    if (ws_size >= needA) {
        // Tier A: everything bf16, all-async GEMMs, split-key attention
        unsigned short* xb  = (unsigned short*)d_ws;
        unsigned short* wqb = xb  + sz_xb;
        unsigned short* wkb = wqb + sz_wq;
        unsigned short* wvb = wkb + sz_wk;
        unsigned short* wob = wvb + sz_wk;
        unsigned short* Qw  = wob + sz_wq;
        unsigned short* Kw  = Qw  + sz_q;
        unsigned short* VTw = Kw  + sz_k;
        // attn partials alias the dead xb/wq/wk/wv pool (42 MB > 33.7 MB)
        float* Opart = (float*)d_ws;                       // 512*64*256 f32
        float* lpart = Opart + (size_t)512 * 64 * 256;     // 512*64 f32
        unsigned short* ATT = Qw;             // in place over Q (same layout)

        cvt_bf16<<<2048, 256, 0, stream>>>(x,   xb,  (int)(sz_xb / 4));
        cvt_bf16<<<2048, 256, 0, stream>>>(q_w, wqb, (int)(sz_wq / 4));
        cvt_bf16<<<1024, 256, 0, stream>>>(k_w, wkb, (int)(sz_wk / 4));
        cvt_bf16<<<1024, 256, 0, stream>>>(v_w, wvb, (int)(sz_wk / 4));
        cvt_bf16<<<2048, 256, 0, stream>>>(o_w, wob, (int)(sz_wq / 4));

        gemm_k<unsigned short, unsigned short, unsigned short, false>
            <<<dim3(MM/128, NQ /128), 256, 0, stream>>>(xb, wqb, Qw,  MM, NQ,  DD);
        gemm_k<unsigned short, unsigned short, unsigned short, false>
            <<<dim3(MM/128, NKV/128), 256, 0, stream>>>(xb, wkb, Kw,  MM, NKV, DD);
        gemm_k<unsigned short, unsigned short, unsigned short, true>
            <<<dim3(MM/128, NKV/128), 256, 0, stream>>>(xb, wvb, VTw, MM, NKV, DD);

        norm_rope<<<dim3(MM, HH),   256, 0, stream>>>(Qw, qn_w, cosb, sinb, HH);
        norm_rope<<<dim3(MM, HKVV), 256, 0, stream>>>(Kw, kn_w, cosb, sinb, HKVV);

        attn_split<<<dim3(16, 48), 256, 0, stream>>>(Qw, Kw, VTw, ATT, Opart, lpart);
        attn_reduce<<<4096, 256, 0, stream>>>(Opart, lpart, ATT);

        gemm_k<unsigned short, unsigned short, float, false>
            <<<dim3(MM/128, DD/128), 256, 0, stream>>>(ATT, wob, out, MM, DD, NQ);
    } else if (ws_size >= needB) {
        // Tier B: weights bf16; x staged fp32->bf16 in GEMM; ATT reuses wq/wk/wv
        unsigned short* wqb = (unsigned short*)d_ws;
        unsigned short* wkb = wqb + sz_wq;
        unsigned short* wvb = wkb + sz_wk;
        unsigned short* wob = wvb + sz_wk;
        unsigned short* Qw  = wob + sz_wq;
        unsigned short* Kw  = Qw  + sz_q;
        unsigned short* VTw = Kw  + sz_k;
        unsigned short* ATT = wqb;            // alias: wq/wk/wv dead after QKV

        cvt_bf16<<<2048, 256, 0, stream>>>(q_w, wqb, (int)(sz_wq / 4));
        cvt_bf16<<<1024, 256, 0, stream>>>(k_w, wkb, (int)(sz_wk / 4));
        cvt_bf16<<<1024, 256, 0, stream>>>(v_w, wvb, (int)(sz_wk / 4));
        cvt_bf16<<<2048, 256, 0, stream>>>(o_w, wob, (int)(sz_wq / 4));

        gemm_k<float, unsigned short, unsigned short, false>
            <<<dim3(MM/128, NQ /128), 256, 0, stream>>>(x, wqb, Qw,  MM, NQ,  DD);
        gemm_k<float, unsigned short, unsigned short, false>
            <<<dim3(MM/128, NKV/128), 256, 0, stream>>>(x, wkb, Kw,  MM, NKV, DD);
        gemm_k<float, unsigned short, unsigned short, true>
            <<<dim3(MM/128, NKV/128), 256, 0, stream>>>(x, wvb, VTw, MM, NKV, DD);

        norm_rope<<<dim3(MM, HH),   256, 0, stream>>>(Qw, qn_w, cosb, sinb, HH);
        norm_rope<<<dim3(MM, HKVV), 256, 0, stream>>>(Kw, kn_w, cosb, sinb, HKVV);

        attn_kernel<<<dim3(32, HH, BB), 256, 0, stream>>>(Qw, Kw, VTw, ATT);

        gemm_k<unsigned short, unsigned short, float, false>
            <<<dim3(MM/128, DD/128), 256, 0, stream>>>(ATT, wob, out, MM, DD, NQ);
    } else {
        // Tier C: fp32 operands staged with in-reg convert (round-3 style)
        unsigned short* Qw  = (unsigned short*)d_ws;
        unsigned short* Kw  = Qw  + sz_q;
        unsigned short* VTw = Kw  + sz_k;
        unsigned short* ATT = VTw + sz_k;

        gemm_k<float, float, unsigned short, false>
            <<<dim3(MM/128, NQ /128), 256, 0, stream>>>(x, q_w, Qw,  MM, NQ,  DD);
        gemm_k<float, float, unsigned short, false>
            <<<dim3(MM/128, NKV/128), 256, 0, stream>>>(x, k_w, Kw,  MM, NKV, DD);
        gemm_k<float, float, unsigned short, true>
            <<<dim3(MM/128, NKV/128), 256, 0, stream>>>(x, v_w, VTw, MM, NKV, DD);

        norm_rope<<<dim3(MM, HH),   256, 0, stream>>>(Qw, qn_w, cosb, sinb, HH);
        norm_rope<<<dim3(MM, HKVV), 256, 0, stream>>>(Kw, kn_w, cosb, sinb, HKVV);

        attn_kernel<<<dim3(32, HH, BB), 256, 0, stream>>>(Qw, Kw, VTw, ATT);

        gemm_k<unsigned short, float, float, false>
            <<<dim3(MM/128, DD/128), 256, 0, stream>>>(ATT, o_w, out, MM, DD, NQ);
    }
}

// Round 4
// 487.408 us; speedup vs baseline: 1.1314x; 1.1314x over previous
//
#include <hip/hip_runtime.h>
#include <hip/hip_bf16.h>

// Problem constants
#define BB   2
#define SS   2048
#define DD   2560
#define HH   8
#define HKVV 4
#define HDD  256
#define MM   (BB*SS)      // 4096 rows
#define NQ   (HH*HDD)     // 2048
#define NKV  (HKVV*HDD)   // 1024
#define SCALING 0.0625f   // 256^-0.5
#define SOFTCAP 4096.0f
#define CAPC    (1.0f/(3.0f*SOFTCAP*SOFTCAP))  // cubic softcap coefficient
#define M0      20.0f     // fixed softmax max: |scores| <= 16.2 by Cauchy-Schwarz

typedef __attribute__((ext_vector_type(8))) short short8;       // 8 bf16 (4 VGPR)
typedef __attribute__((ext_vector_type(8))) unsigned short ushort8;
typedef __attribute__((ext_vector_type(4))) unsigned short us4;
typedef __attribute__((ext_vector_type(4))) float f32x4;        // MFMA C/D

__device__ __forceinline__ float bf2f(unsigned short u) {
    union { unsigned int i; float f; } v; v.i = ((unsigned int)u) << 16; return v.f;
}
__device__ __forceinline__ unsigned short f2bf(float f) {
    union { float f; unsigned int i; } v; v.f = f;
    return (unsigned short)((v.i + 0x7fffu + ((v.i >> 16) & 1u)) >> 16);
}
__device__ __forceinline__ f32x4 mfma16(short8 a, short8 b, f32x4 c) {
    return __builtin_amdgcn_mfma_f32_16x16x32_bf16(a, b, c, 0, 0, 0);
}

// async global->LDS, 16B per lane (gfx950). LDS dest must be lane-linear.
__device__ __forceinline__ void async_cp16(const void* g, void* l) {
    __builtin_amdgcn_global_load_lds(
        (__attribute__((address_space(1))) void*)(g),
        (__attribute__((address_space(3))) void*)(l), 16, 0, 0);
}

// dtype-polymorphic helpers
__device__ __forceinline__ ushort8 ld8(const unsigned short* p) { return *(const ushort8*)p; }
__device__ __forceinline__ ushort8 ld8(const float* p) {
    ushort8 r;
#pragma unroll
    for (int i = 0; i < 8; i++) r[i] = f2bf(p[i]);
    return r;
}
__device__ __forceinline__ void stc(float* p, float v)          { *p = v; }
__device__ __forceinline__ void stc(unsigned short* p, float v) { *p = f2bf(v); }
// staging: bf16 source -> async DMA; fp32 source -> in-reg convert + LDS write
__device__ __forceinline__ void stage8(const unsigned short* src, unsigned short* lds) {
    async_cp16(src, lds);
}
__device__ __forceinline__ void stage8(const float* src, unsigned short* lds) {
    *(ushort8*)lds = ld8(src);
}

// ---------------------------------------------------------------------------
// fp32 -> bf16 bulk convert (RNE), float4-vectorized grid-stride
// ---------------------------------------------------------------------------
__global__ __launch_bounds__(256) void cvt_bf16(const float* __restrict__ in,
                                                unsigned short* __restrict__ out, int n4)
{
    int i = blockIdx.x * 256 + threadIdx.x;
    const int stride = gridDim.x * 256;
    for (; i < n4; i += stride) {
        float4 v = ((const float4*)in)[i];
        us4 o;
        o[0] = f2bf(v.x); o[1] = f2bf(v.y); o[2] = f2bf(v.z); o[3] = f2bf(v.w);
        ((us4*)out)[i] = o;
    }
}

// all four weight matrices in one launch; dst pool is contiguous
// (wq | wk | wv | wo), blockIdx.y selects the tensor.
__global__ __launch_bounds__(256) void cvt_w4(const float* __restrict__ s0,
                                              const float* __restrict__ s1,
                                              const float* __restrict__ s2,
                                              const float* __restrict__ s3,
                                              unsigned short* __restrict__ dst)
{
    const int y = blockIdx.y;
    const int n4q = (int)((size_t)NQ  * DD / 4);   // 1310720
    const int n4k = (int)((size_t)NKV * DD / 4);   //  655360
    const float* src; int n4; size_t off4;
    if (y == 0)      { src = s0; n4 = n4q; off4 = 0; }
    else if (y == 1) { src = s1; n4 = n4k; off4 = (size_t)n4q; }
    else if (y == 2) { src = s2; n4 = n4k; off4 = (size_t)n4q + n4k; }
    else             { src = s3; n4 = n4q; off4 = (size_t)n4q + 2 * (size_t)n4k; }
    us4* out = (us4*)dst + off4;
    int i = blockIdx.x * 256 + threadIdx.x;
    const int stride = gridDim.x * 256;
    for (; i < n4; i += stride) {
        float4 v = ((const float4*)src)[i];
        us4 o;
        o[0] = f2bf(v.x); o[1] = f2bf(v.y); o[2] = f2bf(v.z); o[3] = f2bf(v.w);
        out[i] = o;
    }
}

// ---------------------------------------------------------------------------
// Unified GEMM: C(M,N) = A(M,K) @ B(N,K)^T. bf16 operands staged via
// global_load_lds(16B); fp32 operands converted in-reg. 128x128 tile, 4
// waves. VT_OUT: epilogue writes V^T (b,kvh,d,s) instead of row-major C.
// ---------------------------------------------------------------------------
template<typename TA, typename TB, typename TC, bool VT_OUT>
__global__ __launch_bounds__(256) void gemm_k(const TA* __restrict__ A,
                                              const TB* __restrict__ Bm,
                                              TC* __restrict__ C,
                                              int M, int N, int K)
{
    __shared__ __align__(16) unsigned short As[128][32];
    __shared__ __align__(16) unsigned short Bs[128][32];

    const int tid  = threadIdx.x;
    const int bm   = blockIdx.x, bn = blockIdx.y;
    const int wave = tid >> 6, lane = tid & 63;
    const int quad = lane >> 4, lm = lane & 15;
    const int wm = (wave >> 1) * 64, wn = (wave & 1) * 64;

    f32x4 acc[4][4];
#pragma unroll
    for (int i = 0; i < 4; i++)
#pragma unroll
        for (int j = 0; j < 4; j++) acc[i][j] = (f32x4)0.0f;

    unsigned short* AsF = &As[0][0];
    unsigned short* BsF = &Bs[0][0];
    const int grow = tid >> 2;           // 0..63
    const int gcol = (tid & 3) * 8;      // 0,8,16,24
    const TA* Ab = A  + (size_t)(bm * 128) * K;
    const TB* Bb = Bm + (size_t)(bn * 128) * K;

    for (int k0 = 0; k0 < K; k0 += 32) {
        stage8(&Ab[(size_t)(grow     ) * K + k0 + gcol], AsF + tid * 8);
        stage8(&Ab[(size_t)(grow + 64) * K + k0 + gcol], AsF + 2048 + tid * 8);
        stage8(&Bb[(size_t)(grow     ) * K + k0 + gcol], BsF + tid * 8);
        stage8(&Bb[(size_t)(grow + 64) * K + k0 + gcol], BsF + 2048 + tid * 8);
        __syncthreads();   // drains vmcnt/lgkmcnt -> LDS valid

        short8 af[4], bf[4];
#pragma unroll
        for (int t = 0; t < 4; t++) af[t] = *(const short8*)&As[wm + t * 16 + lm][quad * 8];
#pragma unroll
        for (int t = 0; t < 4; t++) bf[t] = *(const short8*)&Bs[wn + t * 16 + lm][quad * 8];
#pragma unroll
        for (int i = 0; i < 4; i++)
#pragma unroll
            for (int j = 0; j < 4; j++)
                acc[i][j] = mfma16(af[i], bf[j], acc[i][j]);
        __syncthreads();
    }

    // C/D layout: row = quad*4 + r, col = lm  [verified m89/m91]
#pragma unroll
    for (int i = 0; i < 4; i++)
#pragma unroll
        for (int j = 0; j < 4; j++) {
            if constexpr (VT_OUT) {
                int row0 = bm * 128 + wm + i * 16 + quad * 4;   // b*SS + s0
                int col  = bn * 128 + wn + j * 16 + lm;         // kvh*HDD + d
                int b    = row0 >> 11, s0 = row0 & (SS - 1);
                int kvh  = col >> 8,   d  = col & (HDD - 1);
                us4 pk;
#pragma unroll
                for (int r = 0; r < 4; r++) pk[r] = f2bf(acc[i][j][r]);
                *(us4*)&C[(((size_t)b * HKVV + kvh) * HDD + d) * SS + s0] = pk;
            } else {
#pragma unroll
                for (int r = 0; r < 4; r++) {
                    int row = bm * 128 + wm + i * 16 + quad * 4 + r;
                    int col = bn * 128 + wn + j * 16 + lm;
                    stc(&C[(size_t)row * N + col], acc[i][j][r]);
                }
            }
        }
}

// ---------------------------------------------------------------------------
// Merged QKV GEMM: A(M,2560) @ [wq; wk; wv](4096,2560)^T in ONE launch.
// The three weight matrices are contiguous in the workspace pool, so B is a
// single 4096x2560 row-major matrix. 1024 blocks (4/CU) vs the old
// 512+256+256 split where K/V ran at 1 block/CU with zero cross-block
// latency hiding. Epilogue routes by output column:
//   col <  2048          -> Q  (row-major, stride NQ)
//   2048 <= col < 3072   -> K  (row-major, stride NKV)
//   col >= 3072          -> V^T (b,kvh,d,s) layout
// ---------------------------------------------------------------------------
template<typename TA>
__global__ __launch_bounds__(256) void gemm_qkv(const TA* __restrict__ A,
                                                const unsigned short* __restrict__ Bm,
                                                unsigned short* __restrict__ Qo,
                                                unsigned short* __restrict__ Ko,
                                                unsigned short* __restrict__ Vo,
                                                int K)
{
    __shared__ __align__(16) unsigned short As[128][32];
    __shared__ __align__(16) unsigned short Bs[128][32];

    const int tid  = threadIdx.x;
    const int bm   = blockIdx.x, bn = blockIdx.y;
    const int wave = tid >> 6, lane = tid & 63;
    const int quad = lane >> 4, lm = lane & 15;
    const int wm = (wave >> 1) * 64, wn = (wave & 1) * 64;

    f32x4 acc[4][4];
#pragma unroll
    for (int i = 0; i < 4; i++)
#pragma unroll
        for (int j = 0; j < 4; j++) acc[i][j] = (f32x4)0.0f;

    unsigned short* AsF = &As[0][0];
    unsigned short* BsF = &Bs[0][0];
    const int grow = tid >> 2;
    const int gcol = (tid & 3) * 8;
    const TA* Ab = A  + (size_t)(bm * 128) * K;
    const unsigned short* Bb = Bm + (size_t)(bn * 128) * K;

    for (int k0 = 0; k0 < K; k0 += 32) {
        stage8(&Ab[(size_t)(grow     ) * K + k0 + gcol], AsF + tid * 8);
        stage8(&Ab[(size_t)(grow + 64) * K + k0 + gcol], AsF + 2048 + tid * 8);
        stage8(&Bb[(size_t)(grow     ) * K + k0 + gcol], BsF + tid * 8);
        stage8(&Bb[(size_t)(grow + 64) * K + k0 + gcol], BsF + 2048 + tid * 8);
        __syncthreads();

        short8 af[4], bf[4];
#pragma unroll
        for (int t = 0; t < 4; t++) af[t] = *(const short8*)&As[wm + t * 16 + lm][quad * 8];
#pragma unroll
        for (int t = 0; t < 4; t++) bf[t] = *(const short8*)&Bs[wn + t * 16 + lm][quad * 8];
#pragma unroll
        for (int i = 0; i < 4; i++)
#pragma unroll
            for (int j = 0; j < 4; j++)
                acc[i][j] = mfma16(af[i], bf[j], acc[i][j]);
        __syncthreads();
    }

#pragma unroll
    for (int i = 0; i < 4; i++)
#pragma unroll
        for (int j = 0; j < 4; j++) {
            const int row0 = bm * 128 + wm + i * 16 + quad * 4;
            const int col  = bn * 128 + wn + j * 16 + lm;
            if (col < 2048) {                    // Q, row-major stride NQ
#pragma unroll
                for (int r = 0; r < 4; r++)
                    Qo[(size_t)(row0 + r) * NQ + col] = f2bf(acc[i][j][r]);
            } else if (col < 3072) {             // K, row-major stride NKV
                const int ck = col - 2048;
#pragma unroll
                for (int r = 0; r < 4; r++)
                    Ko[(size_t)(row0 + r) * NKV + ck] = f2bf(acc[i][j][r]);
            } else {                             // V^T (b,kvh,d,s)
                const int cv = col - 3072;
                const int b = row0 >> 11, s0 = row0 & (SS - 1);
                const int kvh = cv >> 8, d = cv & (HDD - 1);
                us4 pk;
#pragma unroll
                for (int r = 0; r < 4; r++) pk[r] = f2bf(acc[i][j][r]);
                *(us4*)&Vo[(((size_t)b * HKVV + kvh) * HDD + d) * SS + s0] = pk;
            }
        }
}

// ---------------------------------------------------------------------------
// Fused RMSNorm + RoPE in place on bf16 Q and K in ONE launch.
// blockIdx.y < HH -> Q head y; else K head y-HH.
// ---------------------------------------------------------------------------
__global__ __launch_bounds__(256) void norm_rope2(unsigned short* __restrict__ Qx,
                                                  unsigned short* __restrict__ Kx,
                                                  const float* __restrict__ qnw,
                                                  const float* __restrict__ knw,
                                                  const float* __restrict__ cosb,
                                                  const float* __restrict__ sinb)
{
    const int bs = blockIdx.x;
    const int y  = blockIdx.y;                   // 0..HH+HKVV-1
    const int t  = threadIdx.x;
    unsigned short* X; const float* nw; int nheads, h;
    if (y < HH) { X = Qx; nw = qnw; nheads = HH;   h = y; }
    else        { X = Kx; nw = knw; nheads = HKVV; h = y - HH; }

    __shared__ float xs[256];
    __shared__ float red[4];

    const size_t base = ((size_t)bs * nheads + h) * HDD;
    float v = bf2f(X[base + t]);
    xs[t] = v;

    float p = v * v;
#pragma unroll
    for (int off = 32; off >= 1; off >>= 1) p += __shfl_xor(p, off);
    if ((t & 63) == 0) red[t >> 6] = p;
    __syncthreads();
    float sum = red[0] + red[1] + red[2] + red[3];
    float rs  = rsqrtf(sum * (1.0f / HDD) + 1e-6f);

    const int pt = (t + 128) & 255;
    float w1 = 1.0f + nw[t];
    float w2 = 1.0f + nw[pt];
    float normed  = v * rs * w1;
    float partner = xs[pt] * rs * w2;
    float rot = (t < 128) ? -partner : partner;   // rotate_half: [-x2, x1]
    float c = cosb[(size_t)bs * HDD + t];
    float s = sinb[(size_t)bs * HDD + t];
    X[base + t] = f2bf(normed * c + rot * s);
}

// legacy single-tensor variant (Tier C)
__global__ __launch_bounds__(256) void norm_rope(unsigned short* __restrict__ X,
                                                 const float* __restrict__ nw,
                                                 const float* __restrict__ cosb,
                                                 const float* __restrict__ sinb,
                                                 int nheads)
{
    const int bs = blockIdx.x;
    const int h  = blockIdx.y;
    const int t  = threadIdx.x;

    __shared__ float xs[256];
    __shared__ float red[4];

    const size_t base = ((size_t)bs * nheads + h) * HDD;
    float v = bf2f(X[base + t]);
    xs[t] = v;

    float p = v * v;
#pragma unroll
    for (int off = 32; off >= 1; off >>= 1) p += __shfl_xor(p, off);
    if ((t & 63) == 0) red[t >> 6] = p;
    __syncthreads();
    float sum = red[0] + red[1] + red[2] + red[3];
    float rs  = rsqrtf(sum * (1.0f / HDD) + 1e-6f);

    const int pt = (t + 128) & 255;
    float w1 = 1.0f + nw[t];
    float w2 = 1.0f + nw[pt];
    float normed  = v * rs * w1;
    float partner = xs[pt] * rs * w2;
    float rot = (t < 128) ? -partner : partner;
    float c = cosb[(size_t)bs * HDD + t];
    float s = sinb[(size_t)bs * HDD + t];
    X[base + t] = f2bf(normed * c + rot * s);
}

// ---------------------------------------------------------------------------
// Split-key flash attention (Tier A path). Units balanced via unit_tbl
// (heavy-first); fixed-max softmax partials are additive so qb>=16 splits
// its key range across two blocks; attn_reduce combines. Per-step pipe
// profile (round-3 counters): VALU ~47%, LDS ~55%, MFMA ~15-19% -> jointly
// issue-bound; scheduling knobs are exhausted at this decomposition.
// ---------------------------------------------------------------------------
// units sorted by descending tile count: byte = qb<<2 | (single?2:0) | half
__device__ const unsigned char unit_tbl[48] = {
    62, 124, 125, 120, 121,     // 15s:32  31h:32,32  30h:31,31
    58, 116, 117, 112, 113,     // 14s:30  29h:30,30  28h:29,29
    54, 108, 109, 104, 105,     // 13s:28  27h:28,28  26h:27,27
    50, 100, 101,  96,  97,     // 12s:26  25h:26,26  24h:25,25
    46,  92,  93,  88,  89,     // 11s:24  23h:24,24  22h:23,23
    42,  84,  85,  80,  81,     // 10s:22  21h:22,22  20h:21,21
    38,  76,  77,  72,  73,     //  9s:20  19h:20,20  18h:19,19
    34,  68,  69,  64,  65,     //  8s:18  17h:18,18  16h:17,17
    30,  26,  22,  18,  14, 10, 6, 2   // 7s..0s: 16,14,12,10,8,6,4,2
};

__global__ __launch_bounds__(256) void attn_split(const unsigned short* __restrict__ Q,
                                                  const unsigned short* __restrict__ K,
                                                  const unsigned short* __restrict__ VT,
                                                  unsigned short* __restrict__ O,
                                                  float* __restrict__ Opart,
                                                  float* __restrict__ lpart)
{
    const int tid = threadIdx.x, w = tid >> 6, lane = tid & 63;
    const int quad = lane >> 4, lm = lane & 15;
    const int hb = blockIdx.x;                   // 0..15
    const int h = hb & 7, b = hb >> 3, kvh = h >> 1;

    const unsigned int u = unit_tbl[blockIdx.y];
    const int qb = u >> 2;
    const bool single = (u & 2) != 0;
    const int half = u & 1;
    const int q0 = qb * 64;
    const int T  = 2 * (qb + 1);
    const int t_lo = (!single && half) ? (qb + 1) : 0;
    const int t_hi = single ? T : (half ? T : (qb + 1));

    __shared__ __align__(16) unsigned short Ks[2][32 * 256];   // 32 KB, chunk-swizzled, dbuf
    __shared__ __align__(16) unsigned short Vt[256 * 32];      // 16 KB, (d, s), single buf
    __shared__ __align__(16) unsigned short Ps[4 * 512];       // per-wave P, swizzled

    // Q A-fragments: lane holds Q[m=lm][k=quad*8+j] per 32-wide chunk c
    const unsigned short* Qb = Q + (((size_t)b * SS + q0 + w * 16 + lm) * HH + h) * HDD;
    short8 qf[8];
#pragma unroll
    for (int c = 0; c < 8; c++) qf[c] = *(const short8*)&Qb[c * 32 + quad * 8];

    const unsigned short* Kb = K  + (size_t)b * SS * NKV + (size_t)kvh * HDD;    // row s, stride NKV
    const unsigned short* Vb = VT + ((size_t)b * HKVV + kvh) * HDD * (size_t)SS; // row d, stride SS

    f32x4 o_acc[16];
#pragma unroll
    for (int i = 0; i < 16; i++) o_acc[i] = (f32x4)0.0f;
    float l_r[4] = {0.f, 0.f, 0.f, 0.f};

    const int mylo = q0 + w * 16;                // wave's first q-row
    const int row  = mylo + quad * 4;            // + r = C-layout rows

    auto STAGE_K = [&](int bi, int k0) {
#pragma unroll
        for (int p = 0; p < 4; p++) {
            const int slot = p * 256 + tid;
            const int krow = slot >> 5, kc = slot & 31;
            async_cp16(&Kb[(size_t)(k0 + krow) * NKV + ((kc ^ (krow & 7)) * 8)],
                       &Ks[bi][slot * 8]);
        }
    };
    auto STAGE_V = [&](int k0) {
#pragma unroll
        for (int p = 0; p < 4; p++) {
            const int slot = p * 256 + tid;
            const int vd = slot >> 2, vc = slot & 3;
            async_cp16(&Vb[(size_t)vd * SS + k0 + ((vc ^ ((vd >> 1) & 3)) * 8)],
                       &Vt[slot * 8]);
        }
    };

    STAGE_K(0, t_lo * 32);
    STAGE_V(t_lo * 32);
    int cur = 0;

    for (int t = t_lo; t < t_hi; t++) {
        const int k0 = t * 32;
        const bool more = (t + 1 < t_hi);

        if (more) {
            STAGE_K(cur ^ 1, k0 + 32);           // prefetch next K tile
            asm volatile("s_waitcnt vmcnt(8)" ::: "memory");  // K(t) done
        } else {
            asm volatile("s_waitcnt vmcnt(4)" ::: "memory");
        }
        __builtin_amdgcn_s_barrier();            // Ks[cur] valid
        __builtin_amdgcn_sched_barrier(0);

        short8 pf;
        if (k0 <= mylo + 15) {                   // wave has unmasked keys (wave-uniform)
            f32x4 sa0 = (f32x4)0.0f, sa1 = (f32x4)0.0f;
            __builtin_amdgcn_s_setprio(1);
#pragma unroll
            for (int c = 0; c < 8; c++) {
                const int cs = (((c * 4 + quad) ^ (lm & 7))) * 8;   // un-swizzle
                short8 kf0 = *(const short8*)&Ks[cur][lm * 256 + cs];
                short8 kf1 = *(const short8*)&Ks[cur][(16 + lm) * 256 + cs];
                sa0 = mfma16(qf[c], kf0, sa0);
                sa1 = mfma16(qf[c], kf1, sa1);
            }
            __builtin_amdgcn_s_setprio(0);

            const bool msk = (k0 + 31 > mylo);
            float pe[2][4];
#pragma unroll
            for (int t2 = 0; t2 < 2; t2++) {
                const int key = k0 + t2 * 16 + lm;
#pragma unroll
                for (int r = 0; r < 4; r++) {
                    float s = (t2 ? sa1[r] : sa0[r]) * SCALING;
                    s = s - s * s * s * CAPC;            // ~= SOFTCAP*tanh(s/SOFTCAP)
                    float e = __expf(s - M0);
                    if (msk && key > row + r) e = 0.0f;
                    pe[t2][r] = e;
                    l_r[r] += e;
                }
            }

#pragma unroll
            for (int t2 = 0; t2 < 2; t2++)
#pragma unroll
                for (int r = 0; r < 4; r++) {
                    const int g = (t2 * 2 + (lm >> 3)) ^ r ^ quad;
                    Ps[w * 512 + (quad * 4 + r) * 32 + g * 8 + (lm & 7)] = f2bf(pe[t2][r]);
                }
            asm volatile("s_waitcnt lgkmcnt(0)" ::: "memory");
            __builtin_amdgcn_sched_barrier(0);
            const int gr = quad ^ (lm & 3) ^ (lm >> 2);
            pf = *(const short8*)&Ps[w * 512 + lm * 32 + gr * 8];
        }

        if (more) asm volatile("s_waitcnt vmcnt(4)" ::: "memory");  // V(t) done
        else      asm volatile("s_waitcnt vmcnt(0)" ::: "memory");
        __builtin_amdgcn_s_barrier();            // Vt valid
        __builtin_amdgcn_sched_barrier(0);

        if (k0 <= mylo + 15) {
            __builtin_amdgcn_s_setprio(1);
#pragma unroll
            for (int nt = 0; nt < 16; nt++) {
                short8 vf = *(const short8*)&Vt[(nt * 16 + lm) * 32
                                                + ((quad ^ ((lm >> 1) & 3)) * 8)];
                o_acc[nt] = mfma16(pf, vf, o_acc[nt]);
            }
            __builtin_amdgcn_s_setprio(0);
        }

        __builtin_amdgcn_sched_barrier(0);
        __builtin_amdgcn_s_barrier();            // all reads of Vt done
        __builtin_amdgcn_sched_barrier(0);
        if (more) STAGE_V(k0 + 32);
        cur ^= 1;
    }

#pragma unroll
    for (int off = 1; off < 16; off <<= 1)
#pragma unroll
        for (int r = 0; r < 4; r++) l_r[r] += __shfl_xor(l_r[r], off);

    if (single) {
#pragma unroll
        for (int r = 0; r < 4; r++) {
            float inv = 1.0f / l_r[r];
            unsigned short* Ob = O + ((size_t)b * SS + row + r) * NQ + h * HDD;
#pragma unroll
            for (int nt = 0; nt < 16; nt++)
                Ob[nt * 16 + lm] = f2bf(o_acc[nt][r] * inv);
        }
    } else {
        const int slot = (((b * HH + h) * 16 + (qb - 16)) << 1) | half;
        float* Ob = Opart + ((size_t)slot * 64 + w * 16 + quad * 4) * 256;
#pragma unroll
        for (int r = 0; r < 4; r++) {
            if (lm == 0) lpart[slot * 64 + w * 16 + quad * 4 + r] = l_r[r];
#pragma unroll
            for (int nt = 0; nt < 16; nt++)
                Ob[(size_t)r * 256 + nt * 16 + lm] = o_acc[nt][r];
        }
    }
}

// combine the two key-half partials for qb 16..31, normalize, write ATT bf16
__global__ __launch_bounds__(256) void attn_reduce(const float* __restrict__ Op,
                                                   const float* __restrict__ lp,
                                                   unsigned short* __restrict__ ATT)
{
    const int sp  = blockIdx.x >> 4;             // ((b*HH+h)*16 + (qb-16)), 0..255
    const int wr0 = (blockIdx.x & 15) * 4;
    const int r   = threadIdx.x >> 6;            // 0..3
    const int c0  = (threadIdx.x & 63) * 4;
    const int wrow = wr0 + r;
    const int qbm = sp & 15, h = (sp >> 4) & 7, b = sp >> 7;

    const size_t base0 = ((size_t)(sp * 2) * 64 + wrow) * 256;
    const size_t base1 = base0 + (size_t)64 * 256;
    float4 a = *(const float4*)&Op[base0 + c0];
    float4 d = *(const float4*)&Op[base1 + c0];
    float l = lp[sp * 2 * 64 + wrow] + lp[(sp * 2 + 1) * 64 + wrow];
    float inv = 1.0f / l;
    us4 o;
    o[0] = f2bf((a.x + d.x) * inv); o[1] = f2bf((a.y + d.y) * inv);
    o[2] = f2bf((a.z + d.z) * inv); o[3] = f2bf((a.w + d.w) * inv);
    const int srow = (16 + qbm) * 64 + wrow;
    *(us4*)&ATT[(((size_t)b * SS + srow) * HH + h) * HDD + c0] = o;
}

// ---------------------------------------------------------------------------
// Legacy single-pass attention (Tiers B/C: no ws room for partials)
// ---------------------------------------------------------------------------
__global__ __launch_bounds__(256) void attn_kernel(const unsigned short* __restrict__ Q,
                                                   const unsigned short* __restrict__ K,
                                                   const unsigned short* __restrict__ VT,
                                                   unsigned short* __restrict__ O)
{
    const int tid = threadIdx.x, w = tid >> 6, lane = tid & 63;
    const int quad = lane >> 4, lm = lane & 15;
    const int h = blockIdx.y, b = blockIdx.z, kvh = h >> 1;

    const int bx = blockIdx.x;                   // 0..31
    const int qb = (bx & 1) ? (31 - (bx >> 1)) : (bx >> 1);
    const int q0 = qb * 64;
    const int T  = 2 * (qb + 1);                 // 32-key tiles (always >= 2)

    __shared__ __align__(16) unsigned short Ks[2][32 * 256];
    __shared__ __align__(16) unsigned short Vt[2][256 * 32];
    __shared__ __align__(16) unsigned short Ps[4 * 512];

    const unsigned short* Qb = Q + (((size_t)b * SS + q0 + w * 16 + lm) * HH + h) * HDD;
    short8 qf[8];
#pragma unroll
    for (int c = 0; c < 8; c++) qf[c] = *(const short8*)&Qb[c * 32 + quad * 8];

    const unsigned short* Kb = K  + (size_t)b * SS * NKV + (size_t)kvh * HDD;
    const unsigned short* Vb = VT + ((size_t)b * HKVV + kvh) * HDD * (size_t)SS;

    f32x4 o_acc[16];
#pragma unroll
    for (int i = 0; i < 16; i++) o_acc[i] = (f32x4)0.0f;
    float l_r[4] = {0.f, 0.f, 0.f, 0.f};

    const int mylo = q0 + w * 16;
    const int row  = mylo + quad * 4;

    auto STAGE = [&](int bi, int k0) {
#pragma unroll
        for (int p = 0; p < 4; p++) {
            const int slot = p * 256 + tid;
            const int krow = slot >> 5, kc = slot & 31;
            async_cp16(&Kb[(size_t)(k0 + krow) * NKV + ((kc ^ (krow & 7)) * 8)],
                       &Ks[bi][slot * 8]);
            const int vd = slot >> 2, vc = slot & 3;
            async_cp16(&Vb[(size_t)vd * SS + k0 + ((vc ^ ((vd >> 1) & 3)) * 8)],
                       &Vt[bi][slot * 8]);
        }
    };

    STAGE(0, 0);
    int cur = 0;

    for (int t = 0; t < T; t++) {
        const int k0 = t * 32;

        if (t + 1 < T) {
            STAGE(cur ^ 1, k0 + 32);
            asm volatile("s_waitcnt vmcnt(8)" ::: "memory");
        } else {
            asm volatile("s_waitcnt vmcnt(0)" ::: "memory");
        }
        __builtin_amdgcn_s_barrier();
        __builtin_amdgcn_sched_barrier(0);

        if (k0 <= mylo + 15) {
            f32x4 sa0 = (f32x4)0.0f, sa1 = (f32x4)0.0f;
            __builtin_amdgcn_s_setprio(1);
#pragma unroll
            for (int c = 0; c < 8; c++) {
                const int cs = (((c * 4 + quad) ^ (lm & 7))) * 8;
                short8 kf0 = *(const short8*)&Ks[cur][lm * 256 + cs];
                short8 kf1 = *(const short8*)&Ks[cur][(16 + lm) * 256 + cs];
                sa0 = mfma16(qf[c], kf0, sa0);
                sa1 = mfma16(qf[c], kf1, sa1);
            }
            __builtin_amdgcn_s_setprio(0);

            const bool msk = (k0 + 31 > mylo);
            float pe[2][4];
#pragma unroll
            for (int t2 = 0; t2 < 2; t2++) {
                const int key = k0 + t2 * 16 + lm;
#pragma unroll
                for (int r = 0; r < 4; r++) {
                    float s = (t2 ? sa1[r] : sa0[r]) * SCALING;
                    s = s - s * s * s * CAPC;
                    float e = __expf(s - M0);
                    if (msk && key > row + r) e = 0.0f;
                    pe[t2][r] = e;
                    l_r[r] += e;
                }
            }

#pragma unroll
            for (int t2 = 0; t2 < 2; t2++)
#pragma unroll
                for (int r = 0; r < 4; r++) {
                    const int g = (t2 * 2 + (lm >> 3)) ^ r ^ quad;
                    Ps[w * 512 + (quad * 4 + r) * 32 + g * 8 + (lm & 7)] = f2bf(pe[t2][r]);
                }
            asm volatile("s_waitcnt lgkmcnt(0)" ::: "memory");
            __builtin_amdgcn_sched_barrier(0);
            const int gr = quad ^ (lm & 3) ^ (lm >> 2);
            short8 pf = *(const short8*)&Ps[w * 512 + lm * 32 + gr * 8];

            __builtin_amdgcn_s_setprio(1);
#pragma unroll
            for (int nt = 0; nt < 16; nt++) {
                short8 vf = *(const short8*)&Vt[cur][(nt * 16 + lm) * 32
                                                    + ((quad ^ ((lm >> 1) & 3)) * 8)];
                o_acc[nt] = mfma16(pf, vf, o_acc[nt]);
            }
            __builtin_amdgcn_s_setprio(0);
        }

        __builtin_amdgcn_sched_barrier(0);
        __builtin_amdgcn_s_barrier();
        __builtin_amdgcn_sched_barrier(0);
        cur ^= 1;
    }

#pragma unroll
    for (int off = 1; off < 16; off <<= 1)
#pragma unroll
        for (int r = 0; r < 4; r++) l_r[r] += __shfl_xor(l_r[r], off);
#pragma unroll
    for (int r = 0; r < 4; r++) {
        float inv = 1.0f / l_r[r];
        unsigned short* Ob = O + ((size_t)b * SS + row + r) * NQ + h * HDD;
#pragma unroll
        for (int nt = 0; nt < 16; nt++)
            Ob[nt * 16 + lm] = f2bf(o_acc[nt][r] * inv);
    }
}

// ---------------------------------------------------------------------------
extern "C" void kernel_launch(void* const* d_in, const int* in_sizes, int n_in,
                              void* d_out, int out_size, void* d_ws, size_t ws_size,
                              hipStream_t stream)
{
    const float* x    = (const float*)d_in[0];
    const float* cosb = (const float*)d_in[1];
    const float* sinb = (const float*)d_in[2];
    // d_in[3] = mask (pure causal + NEG, reimplemented in-kernel)
    const float* q_w  = (const float*)d_in[4];
    const float* k_w  = (const float*)d_in[5];
    const float* v_w  = (const float*)d_in[6];
    const float* o_w  = (const float*)d_in[7];
    const float* qn_w = (const float*)d_in[8];
    const float* kn_w = (const float*)d_in[9];
    float* out = (float*)d_out;

    const size_t sz_xb = (size_t)MM * DD;     // 10485760 shorts
    const size_t sz_wq = (size_t)NQ * DD;     //  5242880
    const size_t sz_wk = (size_t)NKV * DD;    //  2621440
    const size_t sz_q  = (size_t)MM * NQ;     //  8388608
    const size_t sz_k  = (size_t)MM * NKV;    //  4194304

    const size_t needA = (sz_xb + 2 * sz_wq + 2 * sz_wk + sz_q + 2 * sz_k) * 2; // ~86 MB
    const size_t needB = (2 * sz_wq + 2 * sz_wk + sz_q + 2 * sz_k) * 2;         // ~65 MB

    if (ws_size >= needA) {
        // Tier A: everything bf16, merged QKV GEMM, split-key attention
        unsigned short* xb  = (unsigned short*)d_ws;
        unsigned short* wqb = xb  + sz_xb;     // wq | wk | wv | wo contiguous
        unsigned short* wkb = wqb + sz_wq;
        unsigned short* wvb = wkb + sz_wk;
        unsigned short* wob = wvb + sz_wk;
        unsigned short* Qw  = wob + sz_wq;
        unsigned short* Kw  = Qw  + sz_q;
        unsigned short* VTw = Kw  + sz_k;
        // attn partials alias the dead xb/wq/wk/wv pool (42 MB > 33.7 MB)
        float* Opart = (float*)d_ws;                       // 512*64*256 f32
        float* lpart = Opart + (size_t)512 * 64 * 256;     // 512*64 f32
        unsigned short* ATT = Qw;             // in place over Q (same layout)

        cvt_bf16<<<2048, 256, 0, stream>>>(x, xb, (int)(sz_xb / 4));
        cvt_w4<<<dim3(512, 4), 256, 0, stream>>>(q_w, k_w, v_w, o_w, wqb);

        gemm_qkv<unsigned short>
            <<<dim3(MM/128, 4096/128), 256, 0, stream>>>(xb, wqb, Qw, Kw, VTw, DD);

        norm_rope2<<<dim3(MM, HH + HKVV), 256, 0, stream>>>(Qw, Kw, qn_w, kn_w, cosb, sinb);

        attn_split<<<dim3(16, 48), 256, 0, stream>>>(Qw, Kw, VTw, ATT, Opart, lpart);
        attn_reduce<<<4096, 256, 0, stream>>>(Opart, lpart, ATT);

        gemm_k<unsigned short, unsigned short, float, false>
            <<<dim3(MM/128, DD/128), 256, 0, stream>>>(ATT, wob, out, MM, DD, NQ);
    } else if (ws_size >= needB) {
        // Tier B: weights bf16; x staged fp32->bf16 in GEMM; ATT reuses wq/wk/wv
        unsigned short* wqb = (unsigned short*)d_ws;
        unsigned short* wkb = wqb + sz_wq;
        unsigned short* wvb = wkb + sz_wk;
        unsigned short* wob = wvb + sz_wk;
        unsigned short* Qw  = wob + sz_wq;
        unsigned short* Kw  = Qw  + sz_q;
        unsigned short* VTw = Kw  + sz_k;
        unsigned short* ATT = wqb;            // alias: wq/wk/wv dead after QKV

        cvt_w4<<<dim3(512, 4), 256, 0, stream>>>(q_w, k_w, v_w, o_w, wqb);

        gemm_qkv<float>
            <<<dim3(MM/128, 4096/128), 256, 0, stream>>>(x, wqb, Qw, Kw, VTw, DD);

        norm_rope2<<<dim3(MM, HH + HKVV), 256, 0, stream>>>(Qw, Kw, qn_w, kn_w, cosb, sinb);

        attn_kernel<<<dim3(32, HH, BB), 256, 0, stream>>>(Qw, Kw, VTw, ATT);

        gemm_k<unsigned short, unsigned short, float, false>
            <<<dim3(MM/128, DD/128), 256, 0, stream>>>(ATT, wob, out, MM, DD, NQ);
    } else {
        // Tier C: fp32 operands staged with in-reg convert (round-3 style)
        unsigned short* Qw  = (unsigned short*)d_ws;
        unsigned short* Kw  = Qw  + sz_q;
        unsigned short* VTw = Kw  + sz_k;
        unsigned short* ATT = VTw + sz_k;

        gemm_k<float, float, unsigned short, false>
            <<<dim3(MM/128, NQ /128), 256, 0, stream>>>(x, q_w, Qw,  MM, NQ,  DD);
        gemm_k<float, float, unsigned short, false>
            <<<dim3(MM/128, NKV/128), 256, 0, stream>>>(x, k_w, Kw,  MM, NKV, DD);
        gemm_k<float, float, unsigned short, true>
            <<<dim3(MM/128, NKV/128), 256, 0, stream>>>(x, v_w, VTw, MM, NKV, DD);

        norm_rope<<<dim3(MM, HH),   256, 0, stream>>>(Qw, qn_w, cosb, sinb, HH);
        norm_rope<<<dim3(MM, HKVV), 256, 0, stream>>>(Kw, kn_w, cosb, sinb, HKVV);

        attn_kernel<<<dim3(32, HH, BB), 256, 0, stream>>>(Qw, Kw, VTw, ATT);

        gemm_k<unsigned short, float, float, false>
            <<<dim3(MM/128, DD/128), 256, 0, stream>>>(ATT, o_w, out, MM, DD, NQ);
    }
}

// Round 5
// 457.111 us; speedup vs baseline: 1.2064x; 1.0663x over previous
//
#include <hip/hip_runtime.h>
#include <hip/hip_bf16.h>

// Problem constants
#define BB   2
#define SS   2048
#define DD   2560
#define HH   8
#define HKVV 4
#define HDD  256
#define MM   (BB*SS)      // 4096 rows
#define NQ   (HH*HDD)     // 2048
#define NKV  (HKVV*HDD)   // 1024
#define SCALING 0.0625f   // 256^-0.5
#define SOFTCAP 4096.0f
#define CAPC    (1.0f/(3.0f*SOFTCAP*SOFTCAP))  // cubic softcap coefficient
#define M0      20.0f     // fixed softmax max: |scores| <= 16.2 by Cauchy-Schwarz

typedef __attribute__((ext_vector_type(8))) short short8;       // 8 bf16 (4 VGPR)
typedef __attribute__((ext_vector_type(8))) unsigned short ushort8;
typedef __attribute__((ext_vector_type(4))) unsigned short us4;
typedef __attribute__((ext_vector_type(4))) float f32x4;        // MFMA C/D

__device__ __forceinline__ float bf2f(unsigned short u) {
    union { unsigned int i; float f; } v; v.i = ((unsigned int)u) << 16; return v.f;
}
__device__ __forceinline__ unsigned short f2bf(float f) {
    union { float f; unsigned int i; } v; v.f = f;
    return (unsigned short)((v.i + 0x7fffu + ((v.i >> 16) & 1u)) >> 16);
}
__device__ __forceinline__ f32x4 mfma16(short8 a, short8 b, f32x4 c) {
    return __builtin_amdgcn_mfma_f32_16x16x32_bf16(a, b, c, 0, 0, 0);
}

// async global->LDS, 16B per lane (gfx950). LDS dest must be lane-linear.
__device__ __forceinline__ void async_cp16(const void* g, void* l) {
    __builtin_amdgcn_global_load_lds(
        (__attribute__((address_space(1))) void*)(g),
        (__attribute__((address_space(3))) void*)(l), 16, 0, 0);
}

// dtype-polymorphic helpers
__device__ __forceinline__ ushort8 ld8(const unsigned short* p) { return *(const ushort8*)p; }
__device__ __forceinline__ ushort8 ld8(const float* p) {
    ushort8 r;
#pragma unroll
    for (int i = 0; i < 8; i++) r[i] = f2bf(p[i]);
    return r;
}
__device__ __forceinline__ void stc(float* p, float v)          { *p = v; }
__device__ __forceinline__ void stc(unsigned short* p, float v) { *p = f2bf(v); }
// staging: bf16 source -> async DMA; fp32 source -> in-reg convert + LDS write
__device__ __forceinline__ void stage8(const unsigned short* src, unsigned short* lds) {
    async_cp16(src, lds);
}
__device__ __forceinline__ void stage8(const float* src, unsigned short* lds) {
    *(ushort8*)lds = ld8(src);
}

// ---------------------------------------------------------------------------
// fp32 -> bf16 bulk convert (RNE), float4-vectorized grid-stride
// ---------------------------------------------------------------------------
__global__ __launch_bounds__(256) void cvt_bf16(const float* __restrict__ in,
                                                unsigned short* __restrict__ out, int n4)
{
    int i = blockIdx.x * 256 + threadIdx.x;
    const int stride = gridDim.x * 256;
    for (; i < n4; i += stride) {
        float4 v = ((const float4*)in)[i];
        us4 o;
        o[0] = f2bf(v.x); o[1] = f2bf(v.y); o[2] = f2bf(v.z); o[3] = f2bf(v.w);
        ((us4*)out)[i] = o;
    }
}

// all four weight matrices in one launch; dst pool is contiguous
// (wq | wk | wv | wo), blockIdx.y selects the tensor.
__global__ __launch_bounds__(256) void cvt_w4(const float* __restrict__ s0,
                                              const float* __restrict__ s1,
                                              const float* __restrict__ s2,
                                              const float* __restrict__ s3,
                                              unsigned short* __restrict__ dst)
{
    const int y = blockIdx.y;
    const int n4q = (int)((size_t)NQ  * DD / 4);   // 1310720
    const int n4k = (int)((size_t)NKV * DD / 4);   //  655360
    const float* src; int n4; size_t off4;
    if (y == 0)      { src = s0; n4 = n4q; off4 = 0; }
    else if (y == 1) { src = s1; n4 = n4k; off4 = (size_t)n4q; }
    else if (y == 2) { src = s2; n4 = n4k; off4 = (size_t)n4q + n4k; }
    else             { src = s3; n4 = n4q; off4 = (size_t)n4q + 2 * (size_t)n4k; }
    us4* out = (us4*)dst + off4;
    int i = blockIdx.x * 256 + threadIdx.x;
    const int stride = gridDim.x * 256;
    for (; i < n4; i += stride) {
        float4 v = ((const float4*)src)[i];
        us4 o;
        o[0] = f2bf(v.x); o[1] = f2bf(v.y); o[2] = f2bf(v.z); o[3] = f2bf(v.w);
        out[i] = o;
    }
}

// ---------------------------------------------------------------------------
// Unified GEMM: C(M,N) = A(M,K) @ B(N,K)^T. bf16 operands staged via
// global_load_lds(16B); fp32 operands converted in-reg. 128x128 tile, 4
// waves. VT_OUT: epilogue writes V^T (b,kvh,d,s) instead of row-major C.
// ---------------------------------------------------------------------------
template<typename TA, typename TB, typename TC, bool VT_OUT>
__global__ __launch_bounds__(256) void gemm_k(const TA* __restrict__ A,
                                              const TB* __restrict__ Bm,
                                              TC* __restrict__ C,
                                              int M, int N, int K)
{
    __shared__ __align__(16) unsigned short As[128][32];
    __shared__ __align__(16) unsigned short Bs[128][32];

    const int tid  = threadIdx.x;
    const int bm   = blockIdx.x, bn = blockIdx.y;
    const int wave = tid >> 6, lane = tid & 63;
    const int quad = lane >> 4, lm = lane & 15;
    const int wm = (wave >> 1) * 64, wn = (wave & 1) * 64;

    f32x4 acc[4][4];
#pragma unroll
    for (int i = 0; i < 4; i++)
#pragma unroll
        for (int j = 0; j < 4; j++) acc[i][j] = (f32x4)0.0f;

    unsigned short* AsF = &As[0][0];
    unsigned short* BsF = &Bs[0][0];
    const int grow = tid >> 2;           // 0..63
    const int gcol = (tid & 3) * 8;      // 0,8,16,24
    const TA* Ab = A  + (size_t)(bm * 128) * K;
    const TB* Bb = Bm + (size_t)(bn * 128) * K;

    for (int k0 = 0; k0 < K; k0 += 32) {
        stage8(&Ab[(size_t)(grow     ) * K + k0 + gcol], AsF + tid * 8);
        stage8(&Ab[(size_t)(grow + 64) * K + k0 + gcol], AsF + 2048 + tid * 8);
        stage8(&Bb[(size_t)(grow     ) * K + k0 + gcol], BsF + tid * 8);
        stage8(&Bb[(size_t)(grow + 64) * K + k0 + gcol], BsF + 2048 + tid * 8);
        __syncthreads();   // drains vmcnt/lgkmcnt -> LDS valid

        short8 af[4], bf[4];
#pragma unroll
        for (int t = 0; t < 4; t++) af[t] = *(const short8*)&As[wm + t * 16 + lm][quad * 8];
#pragma unroll
        for (int t = 0; t < 4; t++) bf[t] = *(const short8*)&Bs[wn + t * 16 + lm][quad * 8];
#pragma unroll
        for (int i = 0; i < 4; i++)
#pragma unroll
            for (int j = 0; j < 4; j++)
                acc[i][j] = mfma16(af[i], bf[j], acc[i][j]);
        __syncthreads();
    }

    // C/D layout: row = quad*4 + r, col = lm  [verified m89/m91]
#pragma unroll
    for (int i = 0; i < 4; i++)
#pragma unroll
        for (int j = 0; j < 4; j++) {
            if constexpr (VT_OUT) {
                int row0 = bm * 128 + wm + i * 16 + quad * 4;   // b*SS + s0
                int col  = bn * 128 + wn + j * 16 + lm;         // kvh*HDD + d
                int b    = row0 >> 11, s0 = row0 & (SS - 1);
                int kvh  = col >> 8,   d  = col & (HDD - 1);
                us4 pk;
#pragma unroll
                for (int r = 0; r < 4; r++) pk[r] = f2bf(acc[i][j][r]);
                *(us4*)&C[(((size_t)b * HKVV + kvh) * HDD + d) * SS + s0] = pk;
            } else {
#pragma unroll
                for (int r = 0; r < 4; r++) {
                    int row = bm * 128 + wm + i * 16 + quad * 4 + r;
                    int col = bn * 128 + wn + j * 16 + lm;
                    stc(&C[(size_t)row * N + col], acc[i][j][r]);
                }
            }
        }
}

// ---------------------------------------------------------------------------
// 256x256 QKV GEMM, BK=64, 512 threads (8 waves: 2M x 4N), counted-vmcnt
// phase schedule (T3+T4) + full XOR chunk swizzle (T2) + setprio (T5).
//
// Round-4 diagnosis: 2-phase 128^2 structure measured 584 TF on this GEMM
// (matches its known ~600 ceiling; stage+drain+barrier dominates). The
// measured lever past that is the 256^2 phase-split with counted vmcnt.
//
// Schedule per K-tile t (buf cur):  [issue tile t+1 -> buf cur^1 (8 loads);
// vmcnt(8) = waits exactly tile t, t+1 stays in flight] -> barrier ->
// 4 quadrant phases {12 ds_read_b128; lgkmcnt(0); setprio(1); 16 MFMA;
// setprio(0); barrier} -> cur^=1. Race ledger: phases only READ buf[cur];
// DMA writes land only in buf[cur^1]; per-wave vmcnt + barrier makes all
// waves' tile-t loads visible; last phase barrier protects buf[cur] from
// next iteration's staging.
//
// LDS swizzle (both-sides, same involution as attn K): LDS chunk p of row r
// holds global 16B chunk p^(r&7); reads use chunk (ks*4+quad)^(row&7) ->
// 64 lanes spread uniformly 8 accesses/bank (conflict floor).
//
// Grid (16,16) = 256 blocks = 1/CU. Epilogue is route-homogeneous per bn:
// bn<8 -> Q, 8..11 -> K, >=12 -> V^T (b,kvh,d,s).
// ---------------------------------------------------------------------------
__global__ __launch_bounds__(512, 2) void gemm_qkv256(const unsigned short* __restrict__ A,
                                                      const unsigned short* __restrict__ Bm,
                                                      unsigned short* __restrict__ Qo,
                                                      unsigned short* __restrict__ Ko,
                                                      unsigned short* __restrict__ Vo,
                                                      int K)
{
    __shared__ __align__(16) unsigned short Asm[2][256 * 64];   // 2 x 32 KB
    __shared__ __align__(16) unsigned short Bsm[2][256 * 64];   // 2 x 32 KB

    const int tid  = threadIdx.x;
    const int wid  = tid >> 6, lane = tid & 63;
    const int quad = lane >> 4, lm = lane & 15;
    const int wr   = wid >> 2, wc = wid & 3;     // 2M x 4N wave grid
    const int bm   = blockIdx.x, bn = blockIdx.y;

    f32x4 acc[8][4];
#pragma unroll
    for (int i = 0; i < 8; i++)
#pragma unroll
        for (int j = 0; j < 4; j++) acc[i][j] = (f32x4)0.0f;

    const unsigned short* Ab = A  + (size_t)(bm * 256) * K;
    const unsigned short* Bb = Bm + (size_t)(bn * 256) * K;

    // stage one 256x64 K-tile of A and B into buf (8 loads/thread)
    auto STAGE = [&](int buf, int k0) {
#pragma unroll
        for (int p = 0; p < 4; p++) {
            const int slot = p * 512 + tid;
            const int row = slot >> 3, ch = slot & 7;
            async_cp16(&Ab[(size_t)row * K + k0 + ((ch ^ (row & 7)) * 8)],
                       &Asm[buf][slot * 8]);
        }
#pragma unroll
        for (int p = 0; p < 4; p++) {
            const int slot = p * 512 + tid;
            const int row = slot >> 3, ch = slot & 7;
            async_cp16(&Bb[(size_t)row * K + k0 + ((ch ^ (row & 7)) * 8)],
                       &Bsm[buf][slot * 8]);
        }
    };

#define QKV_PHASE(MH, NH)                                                         \
    do {                                                                          \
        short8 a_[4][2], b_[2][2];                                                \
        _Pragma("unroll")                                                         \
        for (int mi = 0; mi < 4; mi++) {                                          \
            const int arow = wr * 128 + ((MH) * 4 + mi) * 16 + lm;                \
            _Pragma("unroll")                                                     \
            for (int ks = 0; ks < 2; ks++)                                        \
                a_[mi][ks] = *(const short8*)&Asm[cur][arow * 64 +                \
                                (((ks * 4 + quad) ^ (arow & 7)) * 8)];            \
        }                                                                         \
        _Pragma("unroll")                                                         \
        for (int ni = 0; ni < 2; ni++) {                                          \
            const int brow = wc * 64 + ((NH) * 2 + ni) * 16 + lm;                 \
            _Pragma("unroll")                                                     \
            for (int ks = 0; ks < 2; ks++)                                        \
                b_[ni][ks] = *(const short8*)&Bsm[cur][brow * 64 +                \
                                (((ks * 4 + quad) ^ (brow & 7)) * 8)];            \
        }                                                                         \
        asm volatile("s_waitcnt lgkmcnt(0)" ::: "memory");                        \
        __builtin_amdgcn_sched_barrier(0);                                        \
        __builtin_amdgcn_s_setprio(1);                                            \
        _Pragma("unroll")                                                         \
        for (int mi = 0; mi < 4; mi++)                                            \
            _Pragma("unroll")                                                     \
            for (int ni = 0; ni < 2; ni++)                                        \
                _Pragma("unroll")                                                 \
                for (int ks = 0; ks < 2; ks++)                                    \
                    acc[(MH) * 4 + mi][(NH) * 2 + ni] =                           \
                        mfma16(a_[mi][ks], b_[ni][ks],                            \
                               acc[(MH) * 4 + mi][(NH) * 2 + ni]);                \
        __builtin_amdgcn_s_setprio(0);                                            \
        __builtin_amdgcn_s_barrier();                                             \
        __builtin_amdgcn_sched_barrier(0);                                        \
    } while (0)

    const int NT = K >> 6;                       // 40 K-tiles
    STAGE(0, 0);
    int cur = 0;

    for (int t = 0; t < NT; t++) {
        if (t + 1 < NT) {
            STAGE(cur ^ 1, (t + 1) * 64);        // prefetch next tile
            asm volatile("s_waitcnt vmcnt(8)" ::: "memory");   // tile t landed
        } else {
            asm volatile("s_waitcnt vmcnt(0)" ::: "memory");
        }
        __builtin_amdgcn_s_barrier();            // buf[cur] valid for all waves
        __builtin_amdgcn_sched_barrier(0);

        QKV_PHASE(0, 0);
        QKV_PHASE(0, 1);
        QKV_PHASE(1, 0);
        QKV_PHASE(1, 1);                         // final barrier frees buf[cur]
        cur ^= 1;
    }
#undef QKV_PHASE

    // epilogue: C row = bm*256 + wr*128 + m*16 + quad*4 + r,
    //           C col = bn*256 + wc*64 + n*16 + lm   [same verified mapping]
    if (bn < 8) {                                // Q (row-major, stride NQ)
#pragma unroll
        for (int m = 0; m < 8; m++)
#pragma unroll
            for (int n = 0; n < 4; n++) {
                const int row0 = bm * 256 + wr * 128 + m * 16 + quad * 4;
                const int colg = bn * 256 + wc * 64 + n * 16 + lm;
#pragma unroll
                for (int r = 0; r < 4; r++)
                    Qo[(size_t)(row0 + r) * NQ + colg] = f2bf(acc[m][n][r]);
            }
    } else if (bn < 12) {                        // K (row-major, stride NKV)
#pragma unroll
        for (int m = 0; m < 8; m++)
#pragma unroll
            for (int n = 0; n < 4; n++) {
                const int row0 = bm * 256 + wr * 128 + m * 16 + quad * 4;
                const int ck   = bn * 256 + wc * 64 + n * 16 + lm - 2048;
#pragma unroll
                for (int r = 0; r < 4; r++)
                    Ko[(size_t)(row0 + r) * NKV + ck] = f2bf(acc[m][n][r]);
            }
    } else {                                     // V^T (b,kvh,d,s)
#pragma unroll
        for (int m = 0; m < 8; m++)
#pragma unroll
            for (int n = 0; n < 4; n++) {
                const int row0 = bm * 256 + wr * 128 + m * 16 + quad * 4;
                const int cv   = bn * 256 + wc * 64 + n * 16 + lm - 3072;
                const int b = row0 >> 11, s0 = row0 & (SS - 1);
                const int kvh = cv >> 8, d = cv & (HDD - 1);
                us4 pk;
#pragma unroll
                for (int r = 0; r < 4; r++) pk[r] = f2bf(acc[m][n][r]);
                *(us4*)&Vo[(((size_t)b * HKVV + kvh) * HDD + d) * SS + s0] = pk;
            }
    }
}

// ---------------------------------------------------------------------------
// Merged QKV GEMM, 128^2 (kept for Tier B fp32-A path). Epilogue routes by
// output column: col<2048 -> Q, <3072 -> K, else V^T.
// ---------------------------------------------------------------------------
template<typename TA>
__global__ __launch_bounds__(256) void gemm_qkv(const TA* __restrict__ A,
                                                const unsigned short* __restrict__ Bm,
                                                unsigned short* __restrict__ Qo,
                                                unsigned short* __restrict__ Ko,
                                                unsigned short* __restrict__ Vo,
                                                int K)
{
    __shared__ __align__(16) unsigned short As[128][32];
    __shared__ __align__(16) unsigned short Bs[128][32];

    const int tid  = threadIdx.x;
    const int bm   = blockIdx.x, bn = blockIdx.y;
    const int wave = tid >> 6, lane = tid & 63;
    const int quad = lane >> 4, lm = lane & 15;
    const int wm = (wave >> 1) * 64, wn = (wave & 1) * 64;

    f32x4 acc[4][4];
#pragma unroll
    for (int i = 0; i < 4; i++)
#pragma unroll
        for (int j = 0; j < 4; j++) acc[i][j] = (f32x4)0.0f;

    unsigned short* AsF = &As[0][0];
    unsigned short* BsF = &Bs[0][0];
    const int grow = tid >> 2;
    const int gcol = (tid & 3) * 8;
    const TA* Ab = A  + (size_t)(bm * 128) * K;
    const unsigned short* Bb = Bm + (size_t)(bn * 128) * K;

    for (int k0 = 0; k0 < K; k0 += 32) {
        stage8(&Ab[(size_t)(grow     ) * K + k0 + gcol], AsF + tid * 8);
        stage8(&Ab[(size_t)(grow + 64) * K + k0 + gcol], AsF + 2048 + tid * 8);
        stage8(&Bb[(size_t)(grow     ) * K + k0 + gcol], BsF + tid * 8);
        stage8(&Bb[(size_t)(grow + 64) * K + k0 + gcol], BsF + 2048 + tid * 8);
        __syncthreads();

        short8 af[4], bf[4];
#pragma unroll
        for (int t = 0; t < 4; t++) af[t] = *(const short8*)&As[wm + t * 16 + lm][quad * 8];
#pragma unroll
        for (int t = 0; t < 4; t++) bf[t] = *(const short8*)&Bs[wn + t * 16 + lm][quad * 8];
#pragma unroll
        for (int i = 0; i < 4; i++)
#pragma unroll
            for (int j = 0; j < 4; j++)
                acc[i][j] = mfma16(af[i], bf[j], acc[i][j]);
        __syncthreads();
    }

#pragma unroll
    for (int i = 0; i < 4; i++)
#pragma unroll
        for (int j = 0; j < 4; j++) {
            const int row0 = bm * 128 + wm + i * 16 + quad * 4;
            const int col  = bn * 128 + wn + j * 16 + lm;
            if (col < 2048) {                    // Q, row-major stride NQ
#pragma unroll
                for (int r = 0; r < 4; r++)
                    Qo[(size_t)(row0 + r) * NQ + col] = f2bf(acc[i][j][r]);
            } else if (col < 3072) {             // K, row-major stride NKV
                const int ck = col - 2048;
#pragma unroll
                for (int r = 0; r < 4; r++)
                    Ko[(size_t)(row0 + r) * NKV + ck] = f2bf(acc[i][j][r]);
            } else {                             // V^T (b,kvh,d,s)
                const int cv = col - 3072;
                const int b = row0 >> 11, s0 = row0 & (SS - 1);
                const int kvh = cv >> 8, d = cv & (HDD - 1);
                us4 pk;
#pragma unroll
                for (int r = 0; r < 4; r++) pk[r] = f2bf(acc[i][j][r]);
                *(us4*)&Vo[(((size_t)b * HKVV + kvh) * HDD + d) * SS + s0] = pk;
            }
        }
}

// ---------------------------------------------------------------------------
// Fused RMSNorm + RoPE in place on bf16 Q and K in ONE launch.
// blockIdx.y < HH -> Q head y; else K head y-HH.
// ---------------------------------------------------------------------------
__global__ __launch_bounds__(256) void norm_rope2(unsigned short* __restrict__ Qx,
                                                  unsigned short* __restrict__ Kx,
                                                  const float* __restrict__ qnw,
                                                  const float* __restrict__ knw,
                                                  const float* __restrict__ cosb,
                                                  const float* __restrict__ sinb)
{
    const int bs = blockIdx.x;
    const int y  = blockIdx.y;                   // 0..HH+HKVV-1
    const int t  = threadIdx.x;
    unsigned short* X; const float* nw; int nheads, h;
    if (y < HH) { X = Qx; nw = qnw; nheads = HH;   h = y; }
    else        { X = Kx; nw = knw; nheads = HKVV; h = y - HH; }

    __shared__ float xs[256];
    __shared__ float red[4];

    const size_t base = ((size_t)bs * nheads + h) * HDD;
    float v = bf2f(X[base + t]);
    xs[t] = v;

    float p = v * v;
#pragma unroll
    for (int off = 32; off >= 1; off >>= 1) p += __shfl_xor(p, off);
    if ((t & 63) == 0) red[t >> 6] = p;
    __syncthreads();
    float sum = red[0] + red[1] + red[2] + red[3];
    float rs  = rsqrtf(sum * (1.0f / HDD) + 1e-6f);

    const int pt = (t + 128) & 255;
    float w1 = 1.0f + nw[t];
    float w2 = 1.0f + nw[pt];
    float normed  = v * rs * w1;
    float partner = xs[pt] * rs * w2;
    float rot = (t < 128) ? -partner : partner;   // rotate_half: [-x2, x1]
    float c = cosb[(size_t)bs * HDD + t];
    float s = sinb[(size_t)bs * HDD + t];
    X[base + t] = f2bf(normed * c + rot * s);
}

// legacy single-tensor variant (Tier C)
__global__ __launch_bounds__(256) void norm_rope(unsigned short* __restrict__ X,
                                                 const float* __restrict__ nw,
                                                 const float* __restrict__ cosb,
                                                 const float* __restrict__ sinb,
                                                 int nheads)
{
    const int bs = blockIdx.x;
    const int h  = blockIdx.y;
    const int t  = threadIdx.x;

    __shared__ float xs[256];
    __shared__ float red[4];

    const size_t base = ((size_t)bs * nheads + h) * HDD;
    float v = bf2f(X[base + t]);
    xs[t] = v;

    float p = v * v;
#pragma unroll
    for (int off = 32; off >= 1; off >>= 1) p += __shfl_xor(p, off);
    if ((t & 63) == 0) red[t >> 6] = p;
    __syncthreads();
    float sum = red[0] + red[1] + red[2] + red[3];
    float rs  = rsqrtf(sum * (1.0f / HDD) + 1e-6f);

    const int pt = (t + 128) & 255;
    float w1 = 1.0f + nw[t];
    float w2 = 1.0f + nw[pt];
    float normed  = v * rs * w1;
    float partner = xs[pt] * rs * w2;
    float rot = (t < 128) ? -partner : partner;
    float c = cosb[(size_t)bs * HDD + t];
    float s = sinb[(size_t)bs * HDD + t];
    X[base + t] = f2bf(normed * c + rot * s);
}

// ---------------------------------------------------------------------------
// Split-key flash attention (Tier A path). Units balanced via unit_tbl
// (heavy-first); fixed-max softmax partials are additive so qb>=16 splits
// its key range across two blocks; attn_reduce combines.
// ---------------------------------------------------------------------------
// units sorted by descending tile count: byte = qb<<2 | (single?2:0) | half
__device__ const unsigned char unit_tbl[48] = {
    62, 124, 125, 120, 121,     // 15s:32  31h:32,32  30h:31,31
    58, 116, 117, 112, 113,     // 14s:30  29h:30,30  28h:29,29
    54, 108, 109, 104, 105,     // 13s:28  27h:28,28  26h:27,27
    50, 100, 101,  96,  97,     // 12s:26  25h:26,26  24h:25,25
    46,  92,  93,  88,  89,     // 11s:24  23h:24,24  22h:23,23
    42,  84,  85,  80,  81,     // 10s:22  21h:22,22  20h:21,21
    38,  76,  77,  72,  73,     //  9s:20  19h:20,20  18h:19,19
    34,  68,  69,  64,  65,     //  8s:18  17h:18,18  16h:17,17
    30,  26,  22,  18,  14, 10, 6, 2   // 7s..0s: 16,14,12,10,8,6,4,2
};

__global__ __launch_bounds__(256) void attn_split(const unsigned short* __restrict__ Q,
                                                  const unsigned short* __restrict__ K,
                                                  const unsigned short* __restrict__ VT,
                                                  unsigned short* __restrict__ O,
                                                  float* __restrict__ Opart,
                                                  float* __restrict__ lpart)
{
    const int tid = threadIdx.x, w = tid >> 6, lane = tid & 63;
    const int quad = lane >> 4, lm = lane & 15;
    const int hb = blockIdx.x;                   // 0..15
    const int h = hb & 7, b = hb >> 3, kvh = h >> 1;

    const unsigned int u = unit_tbl[blockIdx.y];
    const int qb = u >> 2;
    const bool single = (u & 2) != 0;
    const int half = u & 1;
    const int q0 = qb * 64;
    const int T  = 2 * (qb + 1);
    const int t_lo = (!single && half) ? (qb + 1) : 0;
    const int t_hi = single ? T : (half ? T : (qb + 1));

    __shared__ __align__(16) unsigned short Ks[2][32 * 256];   // 32 KB, chunk-swizzled, dbuf
    __shared__ __align__(16) unsigned short Vt[256 * 32];      // 16 KB, (d, s), single buf
    __shared__ __align__(16) unsigned short Ps[4 * 512];       // per-wave P, swizzled

    // Q A-fragments: lane holds Q[m=lm][k=quad*8+j] per 32-wide chunk c
    const unsigned short* Qb = Q + (((size_t)b * SS + q0 + w * 16 + lm) * HH + h) * HDD;
    short8 qf[8];
#pragma unroll
    for (int c = 0; c < 8; c++) qf[c] = *(const short8*)&Qb[c * 32 + quad * 8];

    const unsigned short* Kb = K  + (size_t)b * SS * NKV + (size_t)kvh * HDD;    // row s, stride NKV
    const unsigned short* Vb = VT + ((size_t)b * HKVV + kvh) * HDD * (size_t)SS; // row d, stride SS

    f32x4 o_acc[16];
#pragma unroll
    for (int i = 0; i < 16; i++) o_acc[i] = (f32x4)0.0f;
    float l_r[4] = {0.f, 0.f, 0.f, 0.f};

    const int mylo = q0 + w * 16;                // wave's first q-row
    const int row  = mylo + quad * 4;            // + r = C-layout rows

    auto STAGE_K = [&](int bi, int k0) {
#pragma unroll
        for (int p = 0; p < 4; p++) {
            const int slot = p * 256 + tid;
            const int krow = slot >> 5, kc = slot & 31;
            async_cp16(&Kb[(size_t)(k0 + krow) * NKV + ((kc ^ (krow & 7)) * 8)],
                       &Ks[bi][slot * 8]);
        }
    };
    auto STAGE_V = [&](int k0) {
#pragma unroll
        for (int p = 0; p < 4; p++) {
            const int slot = p * 256 + tid;
            const int vd = slot >> 2, vc = slot & 3;
            async_cp16(&Vb[(size_t)vd * SS + k0 + ((vc ^ ((vd >> 1) & 3)) * 8)],
                       &Vt[slot * 8]);
        }
    };

    STAGE_K(0, t_lo * 32);
    STAGE_V(t_lo * 32);
    int cur = 0;

    for (int t = t_lo; t < t_hi; t++) {
        const int k0 = t * 32;
        const bool more = (t + 1 < t_hi);

        if (more) {
            STAGE_K(cur ^ 1, k0 + 32);           // prefetch next K tile
            asm volatile("s_waitcnt vmcnt(8)" ::: "memory");  // K(t) done
        } else {
            asm volatile("s_waitcnt vmcnt(4)" ::: "memory");
        }
        __builtin_amdgcn_s_barrier();            // Ks[cur] valid
        __builtin_amdgcn_sched_barrier(0);

        short8 pf;
        if (k0 <= mylo + 15) {                   // wave has unmasked keys (wave-uniform)
            f32x4 sa0 = (f32x4)0.0f, sa1 = (f32x4)0.0f;
            __builtin_amdgcn_s_setprio(1);
#pragma unroll
            for (int c = 0; c < 8; c++) {
                const int cs = (((c * 4 + quad) ^ (lm & 7))) * 8;   // un-swizzle
                short8 kf0 = *(const short8*)&Ks[cur][lm * 256 + cs];
                short8 kf1 = *(const short8*)&Ks[cur][(16 + lm) * 256 + cs];
                sa0 = mfma16(qf[c], kf0, sa0);
                sa1 = mfma16(qf[c], kf1, sa1);
            }
            __builtin_amdgcn_s_setprio(0);

            const bool msk = (k0 + 31 > mylo);
            float pe[2][4];
#pragma unroll
            for (int t2 = 0; t2 < 2; t2++) {
                const int key = k0 + t2 * 16 + lm;
#pragma unroll
                for (int r = 0; r < 4; r++) {
                    float s = (t2 ? sa1[r] : sa0[r]) * SCALING;
                    s = s - s * s * s * CAPC;            // ~= SOFTCAP*tanh(s/SOFTCAP)
                    float e = __expf(s - M0);
                    if (msk && key > row + r) e = 0.0f;
                    pe[t2][r] = e;
                    l_r[r] += e;
                }
            }

#pragma unroll
            for (int t2 = 0; t2 < 2; t2++)
#pragma unroll
                for (int r = 0; r < 4; r++) {
                    const int g = (t2 * 2 + (lm >> 3)) ^ r ^ quad;
                    Ps[w * 512 + (quad * 4 + r) * 32 + g * 8 + (lm & 7)] = f2bf(pe[t2][r]);
                }
            asm volatile("s_waitcnt lgkmcnt(0)" ::: "memory");
            __builtin_amdgcn_sched_barrier(0);
            const int gr = quad ^ (lm & 3) ^ (lm >> 2);
            pf = *(const short8*)&Ps[w * 512 + lm * 32 + gr * 8];
        }

        if (more) asm volatile("s_waitcnt vmcnt(4)" ::: "memory");  // V(t) done
        else      asm volatile("s_waitcnt vmcnt(0)" ::: "memory");
        __builtin_amdgcn_s_barrier();            // Vt valid
        __builtin_amdgcn_sched_barrier(0);

        if (k0 <= mylo + 15) {
            __builtin_amdgcn_s_setprio(1);
#pragma unroll
            for (int nt = 0; nt < 16; nt++) {
                short8 vf = *(const short8*)&Vt[(nt * 16 + lm) * 32
                                                + ((quad ^ ((lm >> 1) & 3)) * 8)];
                o_acc[nt] = mfma16(pf, vf, o_acc[nt]);
            }
            __builtin_amdgcn_s_setprio(0);
        }

        __builtin_amdgcn_sched_barrier(0);
        __builtin_amdgcn_s_barrier();            // all reads of Vt done
        __builtin_amdgcn_sched_barrier(0);
        if (more) STAGE_V(k0 + 32);
        cur ^= 1;
    }

#pragma unroll
    for (int off = 1; off < 16; off <<= 1)
#pragma unroll
        for (int r = 0; r < 4; r++) l_r[r] += __shfl_xor(l_r[r], off);

    if (single) {
#pragma unroll
        for (int r = 0; r < 4; r++) {
            float inv = 1.0f / l_r[r];
            unsigned short* Ob = O + ((size_t)b * SS + row + r) * NQ + h * HDD;
#pragma unroll
            for (int nt = 0; nt < 16; nt++)
                Ob[nt * 16 + lm] = f2bf(o_acc[nt][r] * inv);
        }
    } else {
        const int slot = (((b * HH + h) * 16 + (qb - 16)) << 1) | half;
        float* Ob = Opart + ((size_t)slot * 64 + w * 16 + quad * 4) * 256;
#pragma unroll
        for (int r = 0; r < 4; r++) {
            if (lm == 0) lpart[slot * 64 + w * 16 + quad * 4 + r] = l_r[r];
#pragma unroll
            for (int nt = 0; nt < 16; nt++)
                Ob[(size_t)r * 256 + nt * 16 + lm] = o_acc[nt][r];
        }
    }
}

// combine the two key-half partials for qb 16..31, normalize, write ATT bf16
__global__ __launch_bounds__(256) void attn_reduce(const float* __restrict__ Op,
                                                   const float* __restrict__ lp,
                                                   unsigned short* __restrict__ ATT)
{
    const int sp  = blockIdx.x >> 4;             // ((b*HH+h)*16 + (qb-16)), 0..255
    const int wr0 = (blockIdx.x & 15) * 4;
    const int r   = threadIdx.x >> 6;            // 0..3
    const int c0  = (threadIdx.x & 63) * 4;
    const int wrow = wr0 + r;
    const int qbm = sp & 15, h = (sp >> 4) & 7, b = sp >> 7;

    const size_t base0 = ((size_t)(sp * 2) * 64 + wrow) * 256;
    const size_t base1 = base0 + (size_t)64 * 256;
    float4 a = *(const float4*)&Op[base0 + c0];
    float4 d = *(const float4*)&Op[base1 + c0];
    float l = lp[sp * 2 * 64 + wrow] + lp[(sp * 2 + 1) * 64 + wrow];
    float inv = 1.0f / l;
    us4 o;
    o[0] = f2bf((a.x + d.x) * inv); o[1] = f2bf((a.y + d.y) * inv);
    o[2] = f2bf((a.z + d.z) * inv); o[3] = f2bf((a.w + d.w) * inv);
    const int srow = (16 + qbm) * 64 + wrow;
    *(us4*)&ATT[(((size_t)b * SS + srow) * HH + h) * HDD + c0] = o;
}

// ---------------------------------------------------------------------------
// Legacy single-pass attention (Tiers B/C: no ws room for partials)
// ---------------------------------------------------------------------------
__global__ __launch_bounds__(256) void attn_kernel(const unsigned short* __restrict__ Q,
                                                   const unsigned short* __restrict__ K,
                                                   const unsigned short* __restrict__ VT,
                                                   unsigned short* __restrict__ O)
{
    const int tid = threadIdx.x, w = tid >> 6, lane = tid & 63;
    const int quad = lane >> 4, lm = lane & 15;
    const int h = blockIdx.y, b = blockIdx.z, kvh = h >> 1;

    const int bx = blockIdx.x;                   // 0..31
    const int qb = (bx & 1) ? (31 - (bx >> 1)) : (bx >> 1);
    const int q0 = qb * 64;
    const int T  = 2 * (qb + 1);                 // 32-key tiles (always >= 2)

    __shared__ __align__(16) unsigned short Ks[2][32 * 256];
    __shared__ __align__(16) unsigned short Vt[2][256 * 32];
    __shared__ __align__(16) unsigned short Ps[4 * 512];

    const unsigned short* Qb = Q + (((size_t)b * SS + q0 + w * 16 + lm) * HH + h) * HDD;
    short8 qf[8];
#pragma unroll
    for (int c = 0; c < 8; c++) qf[c] = *(const short8*)&Qb[c * 32 + quad * 8];

    const unsigned short* Kb = K  + (size_t)b * SS * NKV + (size_t)kvh * HDD;
    const unsigned short* Vb = VT + ((size_t)b * HKVV + kvh) * HDD * (size_t)SS;

    f32x4 o_acc[16];
#pragma unroll
    for (int i = 0; i < 16; i++) o_acc[i] = (f32x4)0.0f;
    float l_r[4] = {0.f, 0.f, 0.f, 0.f};

    const int mylo = q0 + w * 16;
    const int row  = mylo + quad * 4;

    auto STAGE = [&](int bi, int k0) {
#pragma unroll
        for (int p = 0; p < 4; p++) {
            const int slot = p * 256 + tid;
            const int krow = slot >> 5, kc = slot & 31;
            async_cp16(&Kb[(size_t)(k0 + krow) * NKV + ((kc ^ (krow & 7)) * 8)],
                       &Ks[bi][slot * 8]);
            const int vd = slot >> 2, vc = slot & 3;
            async_cp16(&Vb[(size_t)vd * SS + k0 + ((vc ^ ((vd >> 1) & 3)) * 8)],
                       &Vt[bi][slot * 8]);
        }
    };

    STAGE(0, 0);
    int cur = 0;

    for (int t = 0; t < T; t++) {
        const int k0 = t * 32;

        if (t + 1 < T) {
            STAGE(cur ^ 1, k0 + 32);
            asm volatile("s_waitcnt vmcnt(8)" ::: "memory");
        } else {
            asm volatile("s_waitcnt vmcnt(0)" ::: "memory");
        }
        __builtin_amdgcn_s_barrier();
        __builtin_amdgcn_sched_barrier(0);

        if (k0 <= mylo + 15) {
            f32x4 sa0 = (f32x4)0.0f, sa1 = (f32x4)0.0f;
            __builtin_amdgcn_s_setprio(1);
#pragma unroll
            for (int c = 0; c < 8; c++) {
                const int cs = (((c * 4 + quad) ^ (lm & 7))) * 8;
                short8 kf0 = *(const short8*)&Ks[cur][lm * 256 + cs];
                short8 kf1 = *(const short8*)&Ks[cur][(16 + lm) * 256 + cs];
                sa0 = mfma16(qf[c], kf0, sa0);
                sa1 = mfma16(qf[c], kf1, sa1);
            }
            __builtin_amdgcn_s_setprio(0);

            const bool msk = (k0 + 31 > mylo);
            float pe[2][4];
#pragma unroll
            for (int t2 = 0; t2 < 2; t2++) {
                const int key = k0 + t2 * 16 + lm;
#pragma unroll
                for (int r = 0; r < 4; r++) {
                    float s = (t2 ? sa1[r] : sa0[r]) * SCALING;
                    s = s - s * s * s * CAPC;
                    float e = __expf(s - M0);
                    if (msk && key > row + r) e = 0.0f;
                    pe[t2][r] = e;
                    l_r[r] += e;
                }
            }

#pragma unroll
            for (int t2 = 0; t2 < 2; t2++)
#pragma unroll
                for (int r = 0; r < 4; r++) {
                    const int g = (t2 * 2 + (lm >> 3)) ^ r ^ quad;
                    Ps[w * 512 + (quad * 4 + r) * 32 + g * 8 + (lm & 7)] = f2bf(pe[t2][r]);
                }
            asm volatile("s_waitcnt lgkmcnt(0)" ::: "memory");
            __builtin_amdgcn_sched_barrier(0);
            const int gr = quad ^ (lm & 3) ^ (lm >> 2);
            short8 pf = *(const short8*)&Ps[w * 512 + lm * 32 + gr * 8];

            __builtin_amdgcn_s_setprio(1);
#pragma unroll
            for (int nt = 0; nt < 16; nt++) {
                short8 vf = *(const short8*)&Vt[cur][(nt * 16 + lm) * 32
                                                    + ((quad ^ ((lm >> 1) & 3)) * 8)];
                o_acc[nt] = mfma16(pf, vf, o_acc[nt]);
            }
            __builtin_amdgcn_s_setprio(0);
        }

        __builtin_amdgcn_sched_barrier(0);
        __builtin_amdgcn_s_barrier();
        __builtin_amdgcn_sched_barrier(0);
        cur ^= 1;
    }

#pragma unroll
    for (int off = 1; off < 16; off <<= 1)
#pragma unroll
        for (int r = 0; r < 4; r++) l_r[r] += __shfl_xor(l_r[r], off);
#pragma unroll
    for (int r = 0; r < 4; r++) {
        float inv = 1.0f / l_r[r];
        unsigned short* Ob = O + ((size_t)b * SS + row + r) * NQ + h * HDD;
#pragma unroll
        for (int nt = 0; nt < 16; nt++)
            Ob[nt * 16 + lm] = f2bf(o_acc[nt][r] * inv);
    }
}

// ---------------------------------------------------------------------------
extern "C" void kernel_launch(void* const* d_in, const int* in_sizes, int n_in,
                              void* d_out, int out_size, void* d_ws, size_t ws_size,
                              hipStream_t stream)
{
    const float* x    = (const float*)d_in[0];
    const float* cosb = (const float*)d_in[1];
    const float* sinb = (const float*)d_in[2];
    // d_in[3] = mask (pure causal + NEG, reimplemented in-kernel)
    const float* q_w  = (const float*)d_in[4];
    const float* k_w  = (const float*)d_in[5];
    const float* v_w  = (const float*)d_in[6];
    const float* o_w  = (const float*)d_in[7];
    const float* qn_w = (const float*)d_in[8];
    const float* kn_w = (const float*)d_in[9];
    float* out = (float*)d_out;

    const size_t sz_xb = (size_t)MM * DD;     // 10485760 shorts
    const size_t sz_wq = (size_t)NQ * DD;     //  5242880
    const size_t sz_wk = (size_t)NKV * DD;    //  2621440
    const size_t sz_q  = (size_t)MM * NQ;     //  8388608
    const size_t sz_k  = (size_t)MM * NKV;    //  4194304

    const size_t needA = (sz_xb + 2 * sz_wq + 2 * sz_wk + sz_q + 2 * sz_k) * 2; // ~86 MB
    const size_t needB = (2 * sz_wq + 2 * sz_wk + sz_q + 2 * sz_k) * 2;         // ~65 MB

    if (ws_size >= needA) {
        // Tier A: everything bf16, 256^2 phase-scheduled QKV GEMM,
        // split-key attention
        unsigned short* xb  = (unsigned short*)d_ws;
        unsigned short* wqb = xb  + sz_xb;     // wq | wk | wv | wo contiguous
        unsigned short* wkb = wqb + sz_wq;
        unsigned short* wvb = wkb + sz_wk;
        unsigned short* wob = wvb + sz_wk;
        unsigned short* Qw  = wob + sz_wq;
        unsigned short* Kw  = Qw  + sz_q;
        unsigned short* VTw = Kw  + sz_k;
        // attn partials alias the dead xb/wq/wk/wv pool (42 MB > 33.7 MB)
        float* Opart = (float*)d_ws;                       // 512*64*256 f32
        float* lpart = Opart + (size_t)512 * 64 * 256;     // 512*64 f32
        unsigned short* ATT = Qw;             // in place over Q (same layout)

        cvt_bf16<<<2048, 256, 0, stream>>>(x, xb, (int)(sz_xb / 4));
        cvt_w4<<<dim3(512, 4), 256, 0, stream>>>(q_w, k_w, v_w, o_w, wqb);

        gemm_qkv256<<<dim3(MM/256, 4096/256), 512, 0, stream>>>(xb, wqb, Qw, Kw, VTw, DD);

        norm_rope2<<<dim3(MM, HH + HKVV), 256, 0, stream>>>(Qw, Kw, qn_w, kn_w, cosb, sinb);

        attn_split<<<dim3(16, 48), 256, 0, stream>>>(Qw, Kw, VTw, ATT, Opart, lpart);
        attn_reduce<<<4096, 256, 0, stream>>>(Opart, lpart, ATT);

        gemm_k<unsigned short, unsigned short, float, false>
            <<<dim3(MM/128, DD/128), 256, 0, stream>>>(ATT, wob, out, MM, DD, NQ);
    } else if (ws_size >= needB) {
        // Tier B: weights bf16; x staged fp32->bf16 in GEMM; ATT reuses wq/wk/wv
        unsigned short* wqb = (unsigned short*)d_ws;
        unsigned short* wkb = wqb + sz_wq;
        unsigned short* wvb = wkb + sz_wk;
        unsigned short* wob = wvb + sz_wk;
        unsigned short* Qw  = wob + sz_wq;
        unsigned short* Kw  = Qw  + sz_q;
        unsigned short* VTw = Kw  + sz_k;
        unsigned short* ATT = wqb;            // alias: wq/wk/wv dead after QKV

        cvt_w4<<<dim3(512, 4), 256, 0, stream>>>(q_w, k_w, v_w, o_w, wqb);

        gemm_qkv<float>
            <<<dim3(MM/128, 4096/128), 256, 0, stream>>>(x, wqb, Qw, Kw, VTw, DD);

        norm_rope2<<<dim3(MM, HH + HKVV), 256, 0, stream>>>(Qw, Kw, qn_w, kn_w, cosb, sinb);

        attn_kernel<<<dim3(32, HH, BB), 256, 0, stream>>>(Qw, Kw, VTw, ATT);

        gemm_k<unsigned short, unsigned short, float, false>
            <<<dim3(MM/128, DD/128), 256, 0, stream>>>(ATT, wob, out, MM, DD, NQ);
    } else {
        // Tier C: fp32 operands staged with in-reg convert (round-3 style)
        unsigned short* Qw  = (unsigned short*)d_ws;
        unsigned short* Kw  = Qw  + sz_q;
        unsigned short* VTw = Kw  + sz_k;
        unsigned short* ATT = VTw + sz_k;

        gemm_k<float, float, unsigned short, false>
            <<<dim3(MM/128, NQ /128), 256, 0, stream>>>(x, q_w, Qw,  MM, NQ,  DD);
        gemm_k<float, float, unsigned short, false>
            <<<dim3(MM/128, NKV/128), 256, 0, stream>>>(x, k_w, Kw,  MM, NKV, DD);
        gemm_k<float, float, unsigned short, true>
            <<<dim3(MM/128, NKV/128), 256, 0, stream>>>(x, v_w, VTw, MM, NKV, DD);

        norm_rope<<<dim3(MM, HH),   256, 0, stream>>>(Qw, qn_w, cosb, sinb, HH);
        norm_rope<<<dim3(MM, HKVV), 256, 0, stream>>>(Kw, kn_w, cosb, sinb, HKVV);

        attn_kernel<<<dim3(32, HH, BB), 256, 0, stream>>>(Qw, Kw, VTw, ATT);

        gemm_k<unsigned short, float, float, false>
            <<<dim3(MM/128, DD/128), 256, 0, stream>>>(ATT, o_w, out, MM, DD, NQ);
    }
}

// Round 6
// 446.849 us; speedup vs baseline: 1.2341x; 1.0230x over previous
//
#include <hip/hip_runtime.h>
#include <hip/hip_bf16.h>

// Problem constants
#define BB   2
#define SS   2048
#define DD   2560
#define HH   8
#define HKVV 4
#define HDD  256
#define MM   (BB*SS)      // 4096 rows
#define NQ   (HH*HDD)     // 2048
#define NKV  (HKVV*HDD)   // 1024
#define SCALING 0.0625f   // 256^-0.5
#define SOFTCAP 4096.0f
#define CAPC    (1.0f/(3.0f*SOFTCAP*SOFTCAP))  // cubic softcap coefficient
#define M0      20.0f     // fixed softmax max: |scores| <= 16.2 by Cauchy-Schwarz

typedef __attribute__((ext_vector_type(8))) short short8;       // 8 bf16 (4 VGPR)
typedef __attribute__((ext_vector_type(8))) unsigned short ushort8;
typedef __attribute__((ext_vector_type(4))) unsigned short us4;
typedef __attribute__((ext_vector_type(4))) float f32x4;        // MFMA C/D

__device__ __forceinline__ float bf2f(unsigned short u) {
    union { unsigned int i; float f; } v; v.i = ((unsigned int)u) << 16; return v.f;
}
__device__ __forceinline__ unsigned short f2bf(float f) {
    union { float f; unsigned int i; } v; v.f = f;
    return (unsigned short)((v.i + 0x7fffu + ((v.i >> 16) & 1u)) >> 16);
}
__device__ __forceinline__ f32x4 mfma16(short8 a, short8 b, f32x4 c) {
    return __builtin_amdgcn_mfma_f32_16x16x32_bf16(a, b, c, 0, 0, 0);
}

// async global->LDS, 16B per lane (gfx950). LDS dest must be lane-linear.
__device__ __forceinline__ void async_cp16(const void* g, void* l) {
    __builtin_amdgcn_global_load_lds(
        (__attribute__((address_space(1))) void*)(g),
        (__attribute__((address_space(3))) void*)(l), 16, 0, 0);
}

// dtype-polymorphic helpers
__device__ __forceinline__ ushort8 ld8(const unsigned short* p) { return *(const ushort8*)p; }
__device__ __forceinline__ ushort8 ld8(const float* p) {
    ushort8 r;
#pragma unroll
    for (int i = 0; i < 8; i++) r[i] = f2bf(p[i]);
    return r;
}
__device__ __forceinline__ void stc(float* p, float v)          { *p = v; }
__device__ __forceinline__ void stc(unsigned short* p, float v) { *p = f2bf(v); }
// staging: bf16 source -> async DMA; fp32 source -> in-reg convert + LDS write
__device__ __forceinline__ void stage8(const unsigned short* src, unsigned short* lds) {
    async_cp16(src, lds);
}
__device__ __forceinline__ void stage8(const float* src, unsigned short* lds) {
    *(ushort8*)lds = ld8(src);
}

// ---------------------------------------------------------------------------
// fp32 -> bf16 bulk convert (RNE), float4-vectorized grid-stride
// ---------------------------------------------------------------------------
__global__ __launch_bounds__(256) void cvt_bf16(const float* __restrict__ in,
                                                unsigned short* __restrict__ out, int n4)
{
    int i = blockIdx.x * 256 + threadIdx.x;
    const int stride = gridDim.x * 256;
    for (; i < n4; i += stride) {
        float4 v = ((const float4*)in)[i];
        us4 o;
        o[0] = f2bf(v.x); o[1] = f2bf(v.y); o[2] = f2bf(v.z); o[3] = f2bf(v.w);
        ((us4*)out)[i] = o;
    }
}

// all four weight matrices in one launch; dst pool is contiguous
// (wq | wk | wv | wo), blockIdx.y selects the tensor.
__global__ __launch_bounds__(256) void cvt_w4(const float* __restrict__ s0,
                                              const float* __restrict__ s1,
                                              const float* __restrict__ s2,
                                              const float* __restrict__ s3,
                                              unsigned short* __restrict__ dst)
{
    const int y = blockIdx.y;
    const int n4q = (int)((size_t)NQ  * DD / 4);   // 1310720
    const int n4k = (int)((size_t)NKV * DD / 4);   //  655360
    const float* src; int n4; size_t off4;
    if (y == 0)      { src = s0; n4 = n4q; off4 = 0; }
    else if (y == 1) { src = s1; n4 = n4k; off4 = (size_t)n4q; }
    else if (y == 2) { src = s2; n4 = n4k; off4 = (size_t)n4q + n4k; }
    else             { src = s3; n4 = n4q; off4 = (size_t)n4q + 2 * (size_t)n4k; }
    us4* out = (us4*)dst + off4;
    int i = blockIdx.x * 256 + threadIdx.x;
    const int stride = gridDim.x * 256;
    for (; i < n4; i += stride) {
        float4 v = ((const float4*)src)[i];
        us4 o;
        o[0] = f2bf(v.x); o[1] = f2bf(v.y); o[2] = f2bf(v.z); o[3] = f2bf(v.w);
        out[i] = o;
    }
}

// ---------------------------------------------------------------------------
// Unified GEMM: C(M,N) = A(M,K) @ B(N,K)^T. bf16 operands staged via
// global_load_lds(16B); fp32 operands converted in-reg. 128x128 tile, 4
// waves. VT_OUT: epilogue writes V^T (b,kvh,d,s) instead of row-major C.
// ---------------------------------------------------------------------------
template<typename TA, typename TB, typename TC, bool VT_OUT>
__global__ __launch_bounds__(256) void gemm_k(const TA* __restrict__ A,
                                              const TB* __restrict__ Bm,
                                              TC* __restrict__ C,
                                              int M, int N, int K)
{
    __shared__ __align__(16) unsigned short As[128][32];
    __shared__ __align__(16) unsigned short Bs[128][32];

    const int tid  = threadIdx.x;
    const int bm   = blockIdx.x, bn = blockIdx.y;
    const int wave = tid >> 6, lane = tid & 63;
    const int quad = lane >> 4, lm = lane & 15;
    const int wm = (wave >> 1) * 64, wn = (wave & 1) * 64;

    f32x4 acc[4][4];
#pragma unroll
    for (int i = 0; i < 4; i++)
#pragma unroll
        for (int j = 0; j < 4; j++) acc[i][j] = (f32x4)0.0f;

    unsigned short* AsF = &As[0][0];
    unsigned short* BsF = &Bs[0][0];
    const int grow = tid >> 2;           // 0..63
    const int gcol = (tid & 3) * 8;      // 0,8,16,24
    const TA* Ab = A  + (size_t)(bm * 128) * K;
    const TB* Bb = Bm + (size_t)(bn * 128) * K;

    for (int k0 = 0; k0 < K; k0 += 32) {
        stage8(&Ab[(size_t)(grow     ) * K + k0 + gcol], AsF + tid * 8);
        stage8(&Ab[(size_t)(grow + 64) * K + k0 + gcol], AsF + 2048 + tid * 8);
        stage8(&Bb[(size_t)(grow     ) * K + k0 + gcol], BsF + tid * 8);
        stage8(&Bb[(size_t)(grow + 64) * K + k0 + gcol], BsF + 2048 + tid * 8);
        __syncthreads();   // drains vmcnt/lgkmcnt -> LDS valid

        short8 af[4], bf[4];
#pragma unroll
        for (int t = 0; t < 4; t++) af[t] = *(const short8*)&As[wm + t * 16 + lm][quad * 8];
#pragma unroll
        for (int t = 0; t < 4; t++) bf[t] = *(const short8*)&Bs[wn + t * 16 + lm][quad * 8];
#pragma unroll
        for (int i = 0; i < 4; i++)
#pragma unroll
            for (int j = 0; j < 4; j++)
                acc[i][j] = mfma16(af[i], bf[j], acc[i][j]);
        __syncthreads();
    }

    // C/D layout: row = quad*4 + r, col = lm  [verified m89/m91]
#pragma unroll
    for (int i = 0; i < 4; i++)
#pragma unroll
        for (int j = 0; j < 4; j++) {
            if constexpr (VT_OUT) {
                int row0 = bm * 128 + wm + i * 16 + quad * 4;   // b*SS + s0
                int col  = bn * 128 + wn + j * 16 + lm;         // kvh*HDD + d
                int b    = row0 >> 11, s0 = row0 & (SS - 1);
                int kvh  = col >> 8,   d  = col & (HDD - 1);
                us4 pk;
#pragma unroll
                for (int r = 0; r < 4; r++) pk[r] = f2bf(acc[i][j][r]);
                *(us4*)&C[(((size_t)b * HKVV + kvh) * HDD + d) * SS + s0] = pk;
            } else {
#pragma unroll
                for (int r = 0; r < 4; r++) {
                    int row = bm * 128 + wm + i * 16 + quad * 4 + r;
                    int col = bn * 128 + wn + j * 16 + lm;
                    stc(&C[(size_t)row * N + col], acc[i][j][r]);
                }
            }
        }
}

// ---------------------------------------------------------------------------
// 256x256 QKV GEMM, BK=64, 512 threads (8 waves: 2M x 4N), counted-vmcnt
// double-buffer + full XOR chunk swizzle + snake-order register-reuse
// phases.
//
// Round-5 diagnosis: round-4 quadrant phases re-read A per NH and B per MH
// -> 48 ds_read_b128/wave/tile = ~4600 cyc/tile on the LDS pipe (the
// binding pipe; MFMA needs only ~615). Snake order (0,0)->(0,1)->(1,1)->
// (1,0) keeps the live half's fragments in registers: 12+4+8+4 = 28
// reads/wave/tile (-42% on the binding pipe). The per-phase s_barriers
// are also removed: in this buffer discipline phases only READ buf[cur]
// and the DMA writes only buf[cur^1], so only two barriers/tile are
// needed (top: buf valid; end: frees buf for overwrite). Wave drift
// between them gives cross-wave ds_read/MFMA overlap.
//
// Race ledger: per-wave vmcnt(8) at top waits exactly tile t (tile t+1's
// 8 loads stay in flight); top barrier makes all waves' loads mutually
// visible; end barrier orders last read of buf[cur] before iteration t+1
// stages into it.
//
// Grid (16,16) = 256 blocks = 1/CU. Epilogue route-homogeneous per bn:
// bn<8 -> Q, 8..11 -> K, >=12 -> V^T (b,kvh,d,s).
// ---------------------------------------------------------------------------
__global__ __launch_bounds__(512, 2) void gemm_qkv256(const unsigned short* __restrict__ A,
                                                      const unsigned short* __restrict__ Bm,
                                                      unsigned short* __restrict__ Qo,
                                                      unsigned short* __restrict__ Ko,
                                                      unsigned short* __restrict__ Vo,
                                                      int K)
{
    __shared__ __align__(16) unsigned short Asm[2][256 * 64];   // 2 x 32 KB
    __shared__ __align__(16) unsigned short Bsm[2][256 * 64];   // 2 x 32 KB

    const int tid  = threadIdx.x;
    const int wid  = tid >> 6, lane = tid & 63;
    const int quad = lane >> 4, lm = lane & 15;
    const int wr   = wid >> 2, wc = wid & 3;     // 2M x 4N wave grid
    const int bm   = blockIdx.x, bn = blockIdx.y;

    f32x4 acc[8][4];
#pragma unroll
    for (int i = 0; i < 8; i++)
#pragma unroll
        for (int j = 0; j < 4; j++) acc[i][j] = (f32x4)0.0f;

    const unsigned short* Ab = A  + (size_t)(bm * 256) * K;
    const unsigned short* Bb = Bm + (size_t)(bn * 256) * K;

    // stage one 256x64 K-tile of A and B into buf (8 loads/thread)
    auto STAGE = [&](int buf, int k0) {
#pragma unroll
        for (int p = 0; p < 4; p++) {
            const int slot = p * 512 + tid;
            const int row = slot >> 3, ch = slot & 7;
            async_cp16(&Ab[(size_t)row * K + k0 + ((ch ^ (row & 7)) * 8)],
                       &Asm[buf][slot * 8]);
        }
#pragma unroll
        for (int p = 0; p < 4; p++) {
            const int slot = p * 512 + tid;
            const int row = slot >> 3, ch = slot & 7;
            async_cp16(&Bb[(size_t)row * K + k0 + ((ch ^ (row & 7)) * 8)],
                       &Bsm[buf][slot * 8]);
        }
    };

#define LOAD_A(MH)                                                                \
    _Pragma("unroll")                                                             \
    for (int mi = 0; mi < 4; mi++) {                                              \
        const int arow = wr * 128 + ((MH) * 4 + mi) * 16 + lm;                    \
        _Pragma("unroll")                                                         \
        for (int ks = 0; ks < 2; ks++)                                            \
            a_[mi][ks] = *(const short8*)&Asm[cur][arow * 64 +                    \
                            (((ks * 4 + quad) ^ (arow & 7)) * 8)];                \
    }
#define LOAD_B(NH)                                                                \
    _Pragma("unroll")                                                             \
    for (int ni = 0; ni < 2; ni++) {                                              \
        const int brow = wc * 64 + ((NH) * 2 + ni) * 16 + lm;                     \
        _Pragma("unroll")                                                         \
        for (int ks = 0; ks < 2; ks++)                                            \
            b_[ni][ks] = *(const short8*)&Bsm[cur][brow * 64 +                    \
                            (((ks * 4 + quad) ^ (brow & 7)) * 8)];                \
    }
#define MFMA_PH(MH, NH)                                                           \
    asm volatile("s_waitcnt lgkmcnt(0)" ::: "memory");                            \
    __builtin_amdgcn_sched_barrier(0);                                            \
    __builtin_amdgcn_s_setprio(1);                                                \
    _Pragma("unroll")                                                             \
    for (int mi = 0; mi < 4; mi++)                                                \
        _Pragma("unroll")                                                         \
        for (int ni = 0; ni < 2; ni++)                                            \
            _Pragma("unroll")                                                     \
            for (int ks = 0; ks < 2; ks++)                                        \
                acc[(MH) * 4 + mi][(NH) * 2 + ni] =                               \
                    mfma16(a_[mi][ks], b_[ni][ks],                                \
                           acc[(MH) * 4 + mi][(NH) * 2 + ni]);                    \
    __builtin_amdgcn_s_setprio(0);                                                \
    __builtin_amdgcn_sched_barrier(0);

    const int NT = K >> 6;                       // 40 K-tiles
    STAGE(0, 0);
    int cur = 0;

    for (int t = 0; t < NT; t++) {
        if (t + 1 < NT) {
            STAGE(cur ^ 1, (t + 1) * 64);        // prefetch next tile
            asm volatile("s_waitcnt vmcnt(8)" ::: "memory");   // tile t landed
        } else {
            asm volatile("s_waitcnt vmcnt(0)" ::: "memory");
        }
        __builtin_amdgcn_s_barrier();            // buf[cur] valid for all waves
        __builtin_amdgcn_sched_barrier(0);

        short8 a_[4][2], b_[2][2];
        // snake order: reuse A across (0,0)->(0,1), B across (0,1)->(1,1),
        // A across (1,1)->(1,0). 12+4+8+4 = 28 ds_read_b128/wave/tile.
        LOAD_A(0) LOAD_B(0) MFMA_PH(0, 0)
        LOAD_B(1)           MFMA_PH(0, 1)
        LOAD_A(1)           MFMA_PH(1, 1)
        LOAD_B(0)           MFMA_PH(1, 0)

        __builtin_amdgcn_s_barrier();            // all reads of buf[cur] done
        __builtin_amdgcn_sched_barrier(0);       //  -> next iter may overwrite
        cur ^= 1;
    }
#undef LOAD_A
#undef LOAD_B
#undef MFMA_PH

    // epilogue: C row = bm*256 + wr*128 + m*16 + quad*4 + r,
    //           C col = bn*256 + wc*64 + n*16 + lm   [same verified mapping]
    if (bn < 8) {                                // Q (row-major, stride NQ)
#pragma unroll
        for (int m = 0; m < 8; m++)
#pragma unroll
            for (int n = 0; n < 4; n++) {
                const int row0 = bm * 256 + wr * 128 + m * 16 + quad * 4;
                const int colg = bn * 256 + wc * 64 + n * 16 + lm;
#pragma unroll
                for (int r = 0; r < 4; r++)
                    Qo[(size_t)(row0 + r) * NQ + colg] = f2bf(acc[m][n][r]);
            }
    } else if (bn < 12) {                        // K (row-major, stride NKV)
#pragma unroll
        for (int m = 0; m < 8; m++)
#pragma unroll
            for (int n = 0; n < 4; n++) {
                const int row0 = bm * 256 + wr * 128 + m * 16 + quad * 4;
                const int ck   = bn * 256 + wc * 64 + n * 16 + lm - 2048;
#pragma unroll
                for (int r = 0; r < 4; r++)
                    Ko[(size_t)(row0 + r) * NKV + ck] = f2bf(acc[m][n][r]);
            }
    } else {                                     // V^T (b,kvh,d,s)
#pragma unroll
        for (int m = 0; m < 8; m++)
#pragma unroll
            for (int n = 0; n < 4; n++) {
                const int row0 = bm * 256 + wr * 128 + m * 16 + quad * 4;
                const int cv   = bn * 256 + wc * 64 + n * 16 + lm - 3072;
                const int b = row0 >> 11, s0 = row0 & (SS - 1);
                const int kvh = cv >> 8, d = cv & (HDD - 1);
                us4 pk;
#pragma unroll
                for (int r = 0; r < 4; r++) pk[r] = f2bf(acc[m][n][r]);
                *(us4*)&Vo[(((size_t)b * HKVV + kvh) * HDD + d) * SS + s0] = pk;
            }
    }
}

// ---------------------------------------------------------------------------
// Merged QKV GEMM, 128^2 (kept for Tier B fp32-A path). Epilogue routes by
// output column: col<2048 -> Q, <3072 -> K, else V^T.
// ---------------------------------------------------------------------------
template<typename TA>
__global__ __launch_bounds__(256) void gemm_qkv(const TA* __restrict__ A,
                                                const unsigned short* __restrict__ Bm,
                                                unsigned short* __restrict__ Qo,
                                                unsigned short* __restrict__ Ko,
                                                unsigned short* __restrict__ Vo,
                                                int K)
{
    __shared__ __align__(16) unsigned short As[128][32];
    __shared__ __align__(16) unsigned short Bs[128][32];

    const int tid  = threadIdx.x;
    const int bm   = blockIdx.x, bn = blockIdx.y;
    const int wave = tid >> 6, lane = tid & 63;
    const int quad = lane >> 4, lm = lane & 15;
    const int wm = (wave >> 1) * 64, wn = (wave & 1) * 64;

    f32x4 acc[4][4];
#pragma unroll
    for (int i = 0; i < 4; i++)
#pragma unroll
        for (int j = 0; j < 4; j++) acc[i][j] = (f32x4)0.0f;

    unsigned short* AsF = &As[0][0];
    unsigned short* BsF = &Bs[0][0];
    const int grow = tid >> 2;
    const int gcol = (tid & 3) * 8;
    const TA* Ab = A  + (size_t)(bm * 128) * K;
    const unsigned short* Bb = Bm + (size_t)(bn * 128) * K;

    for (int k0 = 0; k0 < K; k0 += 32) {
        stage8(&Ab[(size_t)(grow     ) * K + k0 + gcol], AsF + tid * 8);
        stage8(&Ab[(size_t)(grow + 64) * K + k0 + gcol], AsF + 2048 + tid * 8);
        stage8(&Bb[(size_t)(grow     ) * K + k0 + gcol], BsF + tid * 8);
        stage8(&Bb[(size_t)(grow + 64) * K + k0 + gcol], BsF + 2048 + tid * 8);
        __syncthreads();

        short8 af[4], bf[4];
#pragma unroll
        for (int t = 0; t < 4; t++) af[t] = *(const short8*)&As[wm + t * 16 + lm][quad * 8];
#pragma unroll
        for (int t = 0; t < 4; t++) bf[t] = *(const short8*)&Bs[wn + t * 16 + lm][quad * 8];
#pragma unroll
        for (int i = 0; i < 4; i++)
#pragma unroll
            for (int j = 0; j < 4; j++)
                acc[i][j] = mfma16(af[i], bf[j], acc[i][j]);
        __syncthreads();
    }

#pragma unroll
    for (int i = 0; i < 4; i++)
#pragma unroll
        for (int j = 0; j < 4; j++) {
            const int row0 = bm * 128 + wm + i * 16 + quad * 4;
            const int col  = bn * 128 + wn + j * 16 + lm;
            if (col < 2048) {                    // Q, row-major stride NQ
#pragma unroll
                for (int r = 0; r < 4; r++)
                    Qo[(size_t)(row0 + r) * NQ + col] = f2bf(acc[i][j][r]);
            } else if (col < 3072) {             // K, row-major stride NKV
                const int ck = col - 2048;
#pragma unroll
                for (int r = 0; r < 4; r++)
                    Ko[(size_t)(row0 + r) * NKV + ck] = f2bf(acc[i][j][r]);
            } else {                             // V^T (b,kvh,d,s)
                const int cv = col - 3072;
                const int b = row0 >> 11, s0 = row0 & (SS - 1);
                const int kvh = cv >> 8, d = cv & (HDD - 1);
                us4 pk;
#pragma unroll
                for (int r = 0; r < 4; r++) pk[r] = f2bf(acc[i][j][r]);
                *(us4*)&Vo[(((size_t)b * HKVV + kvh) * HDD + d) * SS + s0] = pk;
            }
        }
}

// ---------------------------------------------------------------------------
// Fused RMSNorm + RoPE in place on bf16 Q and K in ONE launch.
// blockIdx.y < HH -> Q head y; else K head y-HH.
// ---------------------------------------------------------------------------
__global__ __launch_bounds__(256) void norm_rope2(unsigned short* __restrict__ Qx,
                                                  unsigned short* __restrict__ Kx,
                                                  const float* __restrict__ qnw,
                                                  const float* __restrict__ knw,
                                                  const float* __restrict__ cosb,
                                                  const float* __restrict__ sinb)
{
    const int bs = blockIdx.x;
    const int y  = blockIdx.y;                   // 0..HH+HKVV-1
    const int t  = threadIdx.x;
    unsigned short* X; const float* nw; int nheads, h;
    if (y < HH) { X = Qx; nw = qnw; nheads = HH;   h = y; }
    else        { X = Kx; nw = knw; nheads = HKVV; h = y - HH; }

    __shared__ float xs[256];
    __shared__ float red[4];

    const size_t base = ((size_t)bs * nheads + h) * HDD;
    float v = bf2f(X[base + t]);
    xs[t] = v;

    float p = v * v;
#pragma unroll
    for (int off = 32; off >= 1; off >>= 1) p += __shfl_xor(p, off);
    if ((t & 63) == 0) red[t >> 6] = p;
    __syncthreads();
    float sum = red[0] + red[1] + red[2] + red[3];
    float rs  = rsqrtf(sum * (1.0f / HDD) + 1e-6f);

    const int pt = (t + 128) & 255;
    float w1 = 1.0f + nw[t];
    float w2 = 1.0f + nw[pt];
    float normed  = v * rs * w1;
    float partner = xs[pt] * rs * w2;
    float rot = (t < 128) ? -partner : partner;   // rotate_half: [-x2, x1]
    float c = cosb[(size_t)bs * HDD + t];
    float s = sinb[(size_t)bs * HDD + t];
    X[base + t] = f2bf(normed * c + rot * s);
}

// legacy single-tensor variant (Tier C)
__global__ __launch_bounds__(256) void norm_rope(unsigned short* __restrict__ X,
                                                 const float* __restrict__ nw,
                                                 const float* __restrict__ cosb,
                                                 const float* __restrict__ sinb,
                                                 int nheads)
{
    const int bs = blockIdx.x;
    const int h  = blockIdx.y;
    const int t  = threadIdx.x;

    __shared__ float xs[256];
    __shared__ float red[4];

    const size_t base = ((size_t)bs * nheads + h) * HDD;
    float v = bf2f(X[base + t]);
    xs[t] = v;

    float p = v * v;
#pragma unroll
    for (int off = 32; off >= 1; off >>= 1) p += __shfl_xor(p, off);
    if ((t & 63) == 0) red[t >> 6] = p;
    __syncthreads();
    float sum = red[0] + red[1] + red[2] + red[3];
    float rs  = rsqrtf(sum * (1.0f / HDD) + 1e-6f);

    const int pt = (t + 128) & 255;
    float w1 = 1.0f + nw[t];
    float w2 = 1.0f + nw[pt];
    float normed  = v * rs * w1;
    float partner = xs[pt] * rs * w2;
    float rot = (t < 128) ? -partner : partner;
    float c = cosb[(size_t)bs * HDD + t];
    float s = sinb[(size_t)bs * HDD + t];
    X[base + t] = f2bf(normed * c + rot * s);
}

// ---------------------------------------------------------------------------
// Split-key flash attention (Tier A path). Units balanced via unit_tbl
// (heavy-first); fixed-max softmax partials are additive so qb>=16 splits
// its key range across two blocks; attn_reduce combines.
// ---------------------------------------------------------------------------
// units sorted by descending tile count: byte = qb<<2 | (single?2:0) | half
__device__ const unsigned char unit_tbl[48] = {
    62, 124, 125, 120, 121,     // 15s:32  31h:32,32  30h:31,31
    58, 116, 117, 112, 113,     // 14s:30  29h:30,30  28h:29,29
    54, 108, 109, 104, 105,     // 13s:28  27h:28,28  26h:27,27
    50, 100, 101,  96,  97,     // 12s:26  25h:26,26  24h:25,25
    46,  92,  93,  88,  89,     // 11s:24  23h:24,24  22h:23,23
    42,  84,  85,  80,  81,     // 10s:22  21h:22,22  20h:21,21
    38,  76,  77,  72,  73,     //  9s:20  19h:20,20  18h:19,19
    34,  68,  69,  64,  65,     //  8s:18  17h:18,18  16h:17,17
    30,  26,  22,  18,  14, 10, 6, 2   // 7s..0s: 16,14,12,10,8,6,4,2
};

__global__ __launch_bounds__(256) void attn_split(const unsigned short* __restrict__ Q,
                                                  const unsigned short* __restrict__ K,
                                                  const unsigned short* __restrict__ VT,
                                                  unsigned short* __restrict__ O,
                                                  float* __restrict__ Opart,
                                                  float* __restrict__ lpart)
{
    const int tid = threadIdx.x, w = tid >> 6, lane = tid & 63;
    const int quad = lane >> 4, lm = lane & 15;
    const int hb = blockIdx.x;                   // 0..15
    const int h = hb & 7, b = hb >> 3, kvh = h >> 1;

    const unsigned int u = unit_tbl[blockIdx.y];
    const int qb = u >> 2;
    const bool single = (u & 2) != 0;
    const int half = u & 1;
    const int q0 = qb * 64;
    const int T  = 2 * (qb + 1);
    const int t_lo = (!single && half) ? (qb + 1) : 0;
    const int t_hi = single ? T : (half ? T : (qb + 1));

    __shared__ __align__(16) unsigned short Ks[2][32 * 256];   // 32 KB, chunk-swizzled, dbuf
    __shared__ __align__(16) unsigned short Vt[256 * 32];      // 16 KB, (d, s), single buf
    __shared__ __align__(16) unsigned short Ps[4 * 512];       // per-wave P, swizzled

    // Q A-fragments: lane holds Q[m=lm][k=quad*8+j] per 32-wide chunk c
    const unsigned short* Qb = Q + (((size_t)b * SS + q0 + w * 16 + lm) * HH + h) * HDD;
    short8 qf[8];
#pragma unroll
    for (int c = 0; c < 8; c++) qf[c] = *(const short8*)&Qb[c * 32 + quad * 8];

    const unsigned short* Kb = K  + (size_t)b * SS * NKV + (size_t)kvh * HDD;    // row s, stride NKV
    const unsigned short* Vb = VT + ((size_t)b * HKVV + kvh) * HDD * (size_t)SS; // row d, stride SS

    f32x4 o_acc[16];
#pragma unroll
    for (int i = 0; i < 16; i++) o_acc[i] = (f32x4)0.0f;
    float l_r[4] = {0.f, 0.f, 0.f, 0.f};

    const int mylo = q0 + w * 16;                // wave's first q-row
    const int row  = mylo + quad * 4;            // + r = C-layout rows

    auto STAGE_K = [&](int bi, int k0) {
#pragma unroll
        for (int p = 0; p < 4; p++) {
            const int slot = p * 256 + tid;
            const int krow = slot >> 5, kc = slot & 31;
            async_cp16(&Kb[(size_t)(k0 + krow) * NKV + ((kc ^ (krow & 7)) * 8)],
                       &Ks[bi][slot * 8]);
        }
    };
    auto STAGE_V = [&](int k0) {
#pragma unroll
        for (int p = 0; p < 4; p++) {
            const int slot = p * 256 + tid;
            const int vd = slot >> 2, vc = slot & 3;
            async_cp16(&Vb[(size_t)vd * SS + k0 + ((vc ^ ((vd >> 1) & 3)) * 8)],
                       &Vt[slot * 8]);
        }
    };

    STAGE_K(0, t_lo * 32);
    STAGE_V(t_lo * 32);
    int cur = 0;

    for (int t = t_lo; t < t_hi; t++) {
        const int k0 = t * 32;
        const bool more = (t + 1 < t_hi);

        if (more) {
            STAGE_K(cur ^ 1, k0 + 32);           // prefetch next K tile
            asm volatile("s_waitcnt vmcnt(8)" ::: "memory");  // K(t) done
        } else {
            asm volatile("s_waitcnt vmcnt(4)" ::: "memory");
        }
        __builtin_amdgcn_s_barrier();            // Ks[cur] valid
        __builtin_amdgcn_sched_barrier(0);

        short8 pf;
        if (k0 <= mylo + 15) {                   // wave has unmasked keys (wave-uniform)
            f32x4 sa0 = (f32x4)0.0f, sa1 = (f32x4)0.0f;
            __builtin_amdgcn_s_setprio(1);
#pragma unroll
            for (int c = 0; c < 8; c++) {
                const int cs = (((c * 4 + quad) ^ (lm & 7))) * 8;   // un-swizzle
                short8 kf0 = *(const short8*)&Ks[cur][lm * 256 + cs];
                short8 kf1 = *(const short8*)&Ks[cur][(16 + lm) * 256 + cs];
                sa0 = mfma16(qf[c], kf0, sa0);
                sa1 = mfma16(qf[c], kf1, sa1);
            }
            __builtin_amdgcn_s_setprio(0);

            const bool msk = (k0 + 31 > mylo);
            float pe[2][4];
#pragma unroll
            for (int t2 = 0; t2 < 2; t2++) {
                const int key = k0 + t2 * 16 + lm;
#pragma unroll
                for (int r = 0; r < 4; r++) {
                    float s = (t2 ? sa1[r] : sa0[r]) * SCALING;
                    s = s - s * s * s * CAPC;            // ~= SOFTCAP*tanh(s/SOFTCAP)
                    float e = __expf(s - M0);
                    if (msk && key > row + r) e = 0.0f;
                    pe[t2][r] = e;
                    l_r[r] += e;
                }
            }

#pragma unroll
            for (int t2 = 0; t2 < 2; t2++)
#pragma unroll
                for (int r = 0; r < 4; r++) {
                    const int g = (t2 * 2 + (lm >> 3)) ^ r ^ quad;
                    Ps[w * 512 + (quad * 4 + r) * 32 + g * 8 + (lm & 7)] = f2bf(pe[t2][r]);
                }
            asm volatile("s_waitcnt lgkmcnt(0)" ::: "memory");
            __builtin_amdgcn_sched_barrier(0);
            const int gr = quad ^ (lm & 3) ^ (lm >> 2);
            pf = *(const short8*)&Ps[w * 512 + lm * 32 + gr * 8];
        }

        if (more) asm volatile("s_waitcnt vmcnt(4)" ::: "memory");  // V(t) done
        else      asm volatile("s_waitcnt vmcnt(0)" ::: "memory");
        __builtin_amdgcn_s_barrier();            // Vt valid
        __builtin_amdgcn_sched_barrier(0);

        if (k0 <= mylo + 15) {
            __builtin_amdgcn_s_setprio(1);
#pragma unroll
            for (int nt = 0; nt < 16; nt++) {
                short8 vf = *(const short8*)&Vt[(nt * 16 + lm) * 32
                                                + ((quad ^ ((lm >> 1) & 3)) * 8)];
                o_acc[nt] = mfma16(pf, vf, o_acc[nt]);
            }
            __builtin_amdgcn_s_setprio(0);
        }

        __builtin_amdgcn_sched_barrier(0);
        __builtin_amdgcn_s_barrier();            // all reads of Vt done
        __builtin_amdgcn_sched_barrier(0);
        if (more) STAGE_V(k0 + 32);
        cur ^= 1;
    }

#pragma unroll
    for (int off = 1; off < 16; off <<= 1)
#pragma unroll
        for (int r = 0; r < 4; r++) l_r[r] += __shfl_xor(l_r[r], off);

    if (single) {
#pragma unroll
        for (int r = 0; r < 4; r++) {
            float inv = 1.0f / l_r[r];
            unsigned short* Ob = O + ((size_t)b * SS + row + r) * NQ + h * HDD;
#pragma unroll
            for (int nt = 0; nt < 16; nt++)
                Ob[nt * 16 + lm] = f2bf(o_acc[nt][r] * inv);
        }
    } else {
        const int slot = (((b * HH + h) * 16 + (qb - 16)) << 1) | half;
        float* Ob = Opart + ((size_t)slot * 64 + w * 16 + quad * 4) * 256;
#pragma unroll
        for (int r = 0; r < 4; r++) {
            if (lm == 0) lpart[slot * 64 + w * 16 + quad * 4 + r] = l_r[r];
#pragma unroll
            for (int nt = 0; nt < 16; nt++)
                Ob[(size_t)r * 256 + nt * 16 + lm] = o_acc[nt][r];
        }
    }
}

// combine the two key-half partials for qb 16..31, normalize, write ATT bf16
__global__ __launch_bounds__(256) void attn_reduce(const float* __restrict__ Op,
                                                   const float* __restrict__ lp,
                                                   unsigned short* __restrict__ ATT)
{
    const int sp  = blockIdx.x >> 4;             // ((b*HH+h)*16 + (qb-16)), 0..255
    const int wr0 = (blockIdx.x & 15) * 4;
    const int r   = threadIdx.x >> 6;            // 0..3
    const int c0  = (threadIdx.x & 63) * 4;
    const int wrow = wr0 + r;
    const int qbm = sp & 15, h = (sp >> 4) & 7, b = sp >> 7;

    const size_t base0 = ((size_t)(sp * 2) * 64 + wrow) * 256;
    const size_t base1 = base0 + (size_t)64 * 256;
    float4 a = *(const float4*)&Op[base0 + c0];
    float4 d = *(const float4*)&Op[base1 + c0];
    float l = lp[sp * 2 * 64 + wrow] + lp[(sp * 2 + 1) * 64 + wrow];
    float inv = 1.0f / l;
    us4 o;
    o[0] = f2bf((a.x + d.x) * inv); o[1] = f2bf((a.y + d.y) * inv);
    o[2] = f2bf((a.z + d.z) * inv); o[3] = f2bf((a.w + d.w) * inv);
    const int srow = (16 + qbm) * 64 + wrow;
    *(us4*)&ATT[(((size_t)b * SS + srow) * HH + h) * HDD + c0] = o;
}

// ---------------------------------------------------------------------------
// Legacy single-pass attention (Tiers B/C: no ws room for partials)
// ---------------------------------------------------------------------------
__global__ __launch_bounds__(256) void attn_kernel(const unsigned short* __restrict__ Q,
                                                   const unsigned short* __restrict__ K,
                                                   const unsigned short* __restrict__ VT,
                                                   unsigned short* __restrict__ O)
{
    const int tid = threadIdx.x, w = tid >> 6, lane = tid & 63;
    const int quad = lane >> 4, lm = lane & 15;
    const int h = blockIdx.y, b = blockIdx.z, kvh = h >> 1;

    const int bx = blockIdx.x;                   // 0..31
    const int qb = (bx & 1) ? (31 - (bx >> 1)) : (bx >> 1);
    const int q0 = qb * 64;
    const int T  = 2 * (qb + 1);                 // 32-key tiles (always >= 2)

    __shared__ __align__(16) unsigned short Ks[2][32 * 256];
    __shared__ __align__(16) unsigned short Vt[2][256 * 32];
    __shared__ __align__(16) unsigned short Ps[4 * 512];

    const unsigned short* Qb = Q + (((size_t)b * SS + q0 + w * 16 + lm) * HH + h) * HDD;
    short8 qf[8];
#pragma unroll
    for (int c = 0; c < 8; c++) qf[c] = *(const short8*)&Qb[c * 32 + quad * 8];

    const unsigned short* Kb = K  + (size_t)b * SS * NKV + (size_t)kvh * HDD;
    const unsigned short* Vb = VT + ((size_t)b * HKVV + kvh) * HDD * (size_t)SS;

    f32x4 o_acc[16];
#pragma unroll
    for (int i = 0; i < 16; i++) o_acc[i] = (f32x4)0.0f;
    float l_r[4] = {0.f, 0.f, 0.f, 0.f};

    const int mylo = q0 + w * 16;
    const int row  = mylo + quad * 4;

    auto STAGE = [&](int bi, int k0) {
#pragma unroll
        for (int p = 0; p < 4; p++) {
            const int slot = p * 256 + tid;
            const int krow = slot >> 5, kc = slot & 31;
            async_cp16(&Kb[(size_t)(k0 + krow) * NKV + ((kc ^ (krow & 7)) * 8)],
                       &Ks[bi][slot * 8]);
            const int vd = slot >> 2, vc = slot & 3;
            async_cp16(&Vb[(size_t)vd * SS + k0 + ((vc ^ ((vd >> 1) & 3)) * 8)],
                       &Vt[bi][slot * 8]);
        }
    };

    STAGE(0, 0);
    int cur = 0;

    for (int t = 0; t < T; t++) {
        const int k0 = t * 32;

        if (t + 1 < T) {
            STAGE(cur ^ 1, k0 + 32);
            asm volatile("s_waitcnt vmcnt(8)" ::: "memory");
        } else {
            asm volatile("s_waitcnt vmcnt(0)" ::: "memory");
        }
        __builtin_amdgcn_s_barrier();
        __builtin_amdgcn_sched_barrier(0);

        if (k0 <= mylo + 15) {
            f32x4 sa0 = (f32x4)0.0f, sa1 = (f32x4)0.0f;
            __builtin_amdgcn_s_setprio(1);
#pragma unroll
            for (int c = 0; c < 8; c++) {
                const int cs = (((c * 4 + quad) ^ (lm & 7))) * 8;
                short8 kf0 = *(const short8*)&Ks[cur][lm * 256 + cs];
                short8 kf1 = *(const short8*)&Ks[cur][(16 + lm) * 256 + cs];
                sa0 = mfma16(qf[c], kf0, sa0);
                sa1 = mfma16(qf[c], kf1, sa1);
            }
            __builtin_amdgcn_s_setprio(0);

            const bool msk = (k0 + 31 > mylo);
            float pe[2][4];
#pragma unroll
            for (int t2 = 0; t2 < 2; t2++) {
                const int key = k0 + t2 * 16 + lm;
#pragma unroll
                for (int r = 0; r < 4; r++) {
                    float s = (t2 ? sa1[r] : sa0[r]) * SCALING;
                    s = s - s * s * s * CAPC;
                    float e = __expf(s - M0);
                    if (msk && key > row + r) e = 0.0f;
                    pe[t2][r] = e;
                    l_r[r] += e;
                }
            }

#pragma unroll
            for (int t2 = 0; t2 < 2; t2++)
#pragma unroll
                for (int r = 0; r < 4; r++) {
                    const int g = (t2 * 2 + (lm >> 3)) ^ r ^ quad;
                    Ps[w * 512 + (quad * 4 + r) * 32 + g * 8 + (lm & 7)] = f2bf(pe[t2][r]);
                }
            asm volatile("s_waitcnt lgkmcnt(0)" ::: "memory");
            __builtin_amdgcn_sched_barrier(0);
            const int gr = quad ^ (lm & 3) ^ (lm >> 2);
            short8 pf = *(const short8*)&Ps[w * 512 + lm * 32 + gr * 8];

            __builtin_amdgcn_s_setprio(1);
#pragma unroll
            for (int nt = 0; nt < 16; nt++) {
                short8 vf = *(const short8*)&Vt[cur][(nt * 16 + lm) * 32
                                                    + ((quad ^ ((lm >> 1) & 3)) * 8)];
                o_acc[nt] = mfma16(pf, vf, o_acc[nt]);
            }
            __builtin_amdgcn_s_setprio(0);
        }

        __builtin_amdgcn_sched_barrier(0);
        __builtin_amdgcn_s_barrier();
        __builtin_amdgcn_sched_barrier(0);
        cur ^= 1;
    }

#pragma unroll
    for (int off = 1; off < 16; off <<= 1)
#pragma unroll
        for (int r = 0; r < 4; r++) l_r[r] += __shfl_xor(l_r[r], off);
#pragma unroll
    for (int r = 0; r < 4; r++) {
        float inv = 1.0f / l_r[r];
        unsigned short* Ob = O + ((size_t)b * SS + row + r) * NQ + h * HDD;
#pragma unroll
        for (int nt = 0; nt < 16; nt++)
            Ob[nt * 16 + lm] = f2bf(o_acc[nt][r] * inv);
    }
}

// ---------------------------------------------------------------------------
extern "C" void kernel_launch(void* const* d_in, const int* in_sizes, int n_in,
                              void* d_out, int out_size, void* d_ws, size_t ws_size,
                              hipStream_t stream)
{
    const float* x    = (const float*)d_in[0];
    const float* cosb = (const float*)d_in[1];
    const float* sinb = (const float*)d_in[2];
    // d_in[3] = mask (pure causal + NEG, reimplemented in-kernel)
    const float* q_w  = (const float*)d_in[4];
    const float* k_w  = (const float*)d_in[5];
    const float* v_w  = (const float*)d_in[6];
    const float* o_w  = (const float*)d_in[7];
    const float* qn_w = (const float*)d_in[8];
    const float* kn_w = (const float*)d_in[9];
    float* out = (float*)d_out;

    const size_t sz_xb = (size_t)MM * DD;     // 10485760 shorts
    const size_t sz_wq = (size_t)NQ * DD;     //  5242880
    const size_t sz_wk = (size_t)NKV * DD;    //  2621440
    const size_t sz_q  = (size_t)MM * NQ;     //  8388608
    const size_t sz_k  = (size_t)MM * NKV;    //  4194304

    const size_t needA = (sz_xb + 2 * sz_wq + 2 * sz_wk + sz_q + 2 * sz_k) * 2; // ~86 MB
    const size_t needB = (2 * sz_wq + 2 * sz_wk + sz_q + 2 * sz_k) * 2;         // ~65 MB

    if (ws_size >= needA) {
        // Tier A: everything bf16, 256^2 snake-phase QKV GEMM,
        // split-key attention
        unsigned short* xb  = (unsigned short*)d_ws;
        unsigned short* wqb = xb  + sz_xb;     // wq | wk | wv | wo contiguous
        unsigned short* wkb = wqb + sz_wq;
        unsigned short* wvb = wkb + sz_wk;
        unsigned short* wob = wvb + sz_wk;
        unsigned short* Qw  = wob + sz_wq;
        unsigned short* Kw  = Qw  + sz_q;
        unsigned short* VTw = Kw  + sz_k;
        // attn partials alias the dead xb/wq/wk/wv pool (42 MB > 33.7 MB)
        float* Opart = (float*)d_ws;                       // 512*64*256 f32
        float* lpart = Opart + (size_t)512 * 64 * 256;     // 512*64 f32
        unsigned short* ATT = Qw;             // in place over Q (same layout)

        cvt_bf16<<<2048, 256, 0, stream>>>(x, xb, (int)(sz_xb / 4));
        cvt_w4<<<dim3(512, 4), 256, 0, stream>>>(q_w, k_w, v_w, o_w, wqb);

        gemm_qkv256<<<dim3(MM/256, 4096/256), 512, 0, stream>>>(xb, wqb, Qw, Kw, VTw, DD);

        norm_rope2<<<dim3(MM, HH + HKVV), 256, 0, stream>>>(Qw, Kw, qn_w, kn_w, cosb, sinb);

        attn_split<<<dim3(16, 48), 256, 0, stream>>>(Qw, Kw, VTw, ATT, Opart, lpart);
        attn_reduce<<<4096, 256, 0, stream>>>(Opart, lpart, ATT);

        gemm_k<unsigned short, unsigned short, float, false>
            <<<dim3(MM/128, DD/128), 256, 0, stream>>>(ATT, wob, out, MM, DD, NQ);
    } else if (ws_size >= needB) {
        // Tier B: weights bf16; x staged fp32->bf16 in GEMM; ATT reuses wq/wk/wv
        unsigned short* wqb = (unsigned short*)d_ws;
        unsigned short* wkb = wqb + sz_wq;
        unsigned short* wvb = wkb + sz_wk;
        unsigned short* wob = wvb + sz_wk;
        unsigned short* Qw  = wob + sz_wq;
        unsigned short* Kw  = Qw  + sz_q;
        unsigned short* VTw = Kw  + sz_k;
        unsigned short* ATT = wqb;            // alias: wq/wk/wv dead after QKV

        cvt_w4<<<dim3(512, 4), 256, 0, stream>>>(q_w, k_w, v_w, o_w, wqb);

        gemm_qkv<float>
            <<<dim3(MM/128, 4096/128), 256, 0, stream>>>(x, wqb, Qw, Kw, VTw, DD);

        norm_rope2<<<dim3(MM, HH + HKVV), 256, 0, stream>>>(Qw, Kw, qn_w, kn_w, cosb, sinb);

        attn_kernel<<<dim3(32, HH, BB), 256, 0, stream>>>(Qw, Kw, VTw, ATT);

        gemm_k<unsigned short, unsigned short, float, false>
            <<<dim3(MM/128, DD/128), 256, 0, stream>>>(ATT, wob, out, MM, DD, NQ);
    } else {
        // Tier C: fp32 operands staged with in-reg convert (round-3 style)
        unsigned short* Qw  = (unsigned short*)d_ws;
        unsigned short* Kw  = Qw  + sz_q;
        unsigned short* VTw = Kw  + sz_k;
        unsigned short* ATT = VTw + sz_k;

        gemm_k<float, float, unsigned short, false>
            <<<dim3(MM/128, NQ /128), 256, 0, stream>>>(x, q_w, Qw,  MM, NQ,  DD);
        gemm_k<float, float, unsigned short, false>
            <<<dim3(MM/128, NKV/128), 256, 0, stream>>>(x, k_w, Kw,  MM, NKV, DD);
        gemm_k<float, float, unsigned short, true>
            <<<dim3(MM/128, NKV/128), 256, 0, stream>>>(x, v_w, VTw, MM, NKV, DD);

        norm_rope<<<dim3(MM, HH),   256, 0, stream>>>(Qw, qn_w, cosb, sinb, HH);
        norm_rope<<<dim3(MM, HKVV), 256, 0, stream>>>(Kw, kn_w, cosb, sinb, HKVV);

        attn_kernel<<<dim3(32, HH, BB), 256, 0, stream>>>(Qw, Kw, VTw, ATT);

        gemm_k<unsigned short, float, float, false>
            <<<dim3(MM/128, DD/128), 256, 0, stream>>>(ATT, o_w, out, MM, DD, NQ);
    }
}